// Round 11
// baseline (297.904 us; speedup 1.0000x reference)
//
#include <hip/hip_runtime.h>
#include <hip/hip_bf16.h>

typedef __hip_bfloat16 bf16;
typedef __attribute__((ext_vector_type(8))) short short8;
typedef __attribute__((ext_vector_type(4))) float f32x4;
typedef __attribute__((ext_vector_type(2))) float f32x2;

// ---- problem constants (fixed by reference file) ----
#define N_NODES 50000
#define N_EDGES 800000
#define IN_F    128
#define HID     256
#define N_CLS   10
#define N_GRAPH 256

// radix-partition CSR build
#define NB 98          // buckets = ceil(N / 512), bucket = d >> 9
#define PBLOCKS 256    // partition grid (A1/A2 must match exactly)

// flags[0] = ints are int64 (read low words), flags[1] = floats are bf16
__device__ __forceinline__ int IG(const int* __restrict__ p, int i, int w) {
    return w ? p[2 * i] : p[i];
}
__device__ __forceinline__ float LF(const void* __restrict__ p, int i, int isbf) {
    return isbf ? __bfloat162float(((const bf16*)p)[i]) : ((const float*)p)[i];
}
__device__ __forceinline__ float b2f(unsigned short h) {
    union { unsigned u; float f; } c; c.u = ((unsigned)h) << 16; return c.f;
}
__device__ __forceinline__ unsigned short f2b(float x) {
    bf16 h = __float2bfloat16(x);
    union { bf16 b; unsigned short u; } c; c.b = h; return c.u;
}
// fp8 e4m3 byte -> float scaled by 2^-120 (fallback decode path)
__device__ __forceinline__ float f8s(unsigned b) {
    union { unsigned u; float f; } c;
    c.u = ((b & 0x80u) << 24) | ((b & 0x7Fu) << 20);
    return c.f;
}
#define F8SCALE 0x1p120f
// float -> OCP fp8 e4m3 (RTNE via bf16 intermediate; FTZ below subnormal range)
__device__ __forceinline__ unsigned f2fp8(float x) {
    unsigned short h = f2b(x * 0x1p-120f);
    unsigned s = ((unsigned)h >> 8) & 0x80u;
    unsigned mag = (unsigned)h & 0x7FFFu;
    unsigned r = (mag + 7u + ((mag >> 4) & 1u)) >> 4;
    if (r > 0x7Eu) r = 0x7Eu;
    return s | r;
}

#if defined(__has_builtin)
#if __has_builtin(__builtin_amdgcn_cvt_pk_f32_fp8)
#define HW_FP8 1
#endif
#if __has_builtin(__builtin_amdgcn_cvt_pk_fp8_f32)
#define HW_FP8E 1
#endif
#endif

// decode 2 fp8 bytes (low or high half of a dword) -> float2, true magnitudes
__device__ __forceinline__ f32x2 cvt2lo(unsigned v) {
#ifdef HW_FP8
    return __builtin_amdgcn_cvt_pk_f32_fp8((int)v, false);
#else
    f32x2 r; r[0] = f8s(v & 0xFF) * F8SCALE; r[1] = f8s((v >> 8) & 0xFF) * F8SCALE; return r;
#endif
}
__device__ __forceinline__ f32x2 cvt2hi(unsigned v) {
#ifdef HW_FP8
    return __builtin_amdgcn_cvt_pk_f32_fp8((int)v, true);
#else
    f32x2 r; r[0] = f8s((v >> 16) & 0xFF) * F8SCALE; r[1] = f8s(v >> 24) * F8SCALE; return r;
#endif
}
// pack 4 floats -> 4 fp8 bytes (HW packed cvt when available)
__device__ __forceinline__ unsigned pk4_fp8(float v0, float v1, float v2, float v3) {
#ifdef HW_FP8E
    int o = __builtin_amdgcn_cvt_pk_fp8_f32(v0, v1, 0, false);
    o = __builtin_amdgcn_cvt_pk_fp8_f32(v2, v3, o, true);
    return (unsigned)o;
#else
    return f2fp8(v0) | (f2fp8(v1) << 8) | (f2fp8(v2) << 16) | (f2fp8(v3) << 24);
#endif
}

// ---- combined dtype detectors (1 block) ----
__global__ __launch_bounds__(256) void k_detect(const int* __restrict__ ei,
                                                const unsigned short* __restrict__ x,
                                                int* __restrict__ flags) {
    __shared__ int nz, cnt;
    if (threadIdx.x == 0) { nz = 0; cnt = 0; }
    __syncthreads();
    int found = 0, c = 0;
    for (int s = 0; s < 4; ++s) {
        int idx = 2 * (threadIdx.x * 4 + s) + 1;
        if (ei[idx] != 0) found = 1;
    }
    for (int s = 0; s < 8; ++s) {
        unsigned short h = x[threadIdx.x * 8 + s];
        int e = (h >> 7) & 0xFF;
        if (e >= 110 && e <= 135) c++;
    }
    if (found) atomicAdd(&nz, 1);
    atomicAdd(&cnt, c);
    __syncthreads();
    if (threadIdx.x == 0) {
        flags[0] = (nz == 0) ? 1 : 0;
        flags[1] = (cnt > 1536) ? 1 : 0;
    }
}

// ---- partition pass A1: LDS bucket histogram -> reserve global bases ----
// bucketCnt is padded: count for bucket q lives at bucketCnt[q*16] (one 64B line each)
__global__ __launch_bounds__(256) void k_partA1(const int* __restrict__ ei, int* __restrict__ bucketCnt,
                                                int* __restrict__ blockBase, const int* __restrict__ flags,
                                                int E, int N) {
    __shared__ int h[NB];
    int t = threadIdx.x;
    if (t < NB) h[t] = 0;
    __syncthreads();
    int w = flags[0];
    for (int e = blockIdx.x * 256 + t; e < E; e += PBLOCKS * 256) {
        int d = IG(ei, E + e, w);
        int s = IG(ei, e, w);
        if ((unsigned)d < (unsigned)N && (unsigned)s < (unsigned)N)
            atomicAdd(&h[d >> 9], 1);
    }
    __syncthreads();
    if (t < NB)
        blockBase[blockIdx.x * NB + t] = atomicAdd(&bucketCnt[t * 16], h[t]);
}

// ---- 1-block exclusive scan of bucket counts ----
__global__ __launch_bounds__(128) void k_bscan(const int* __restrict__ bucketCnt,
                                               int* __restrict__ bucketBase) {
    __shared__ int s[128];
    int t = threadIdx.x;
    int v = (t < NB) ? bucketCnt[t * 16] : 0;
    s[t] = v;
    __syncthreads();
    for (int off = 1; off < 128; off <<= 1) {
        int add = (t >= off) ? s[t - off] : 0;
        __syncthreads();
        s[t] += add;
        __syncthreads();
    }
    if (t <= NB) bucketBase[t] = (t < NB) ? (s[t] - v) : s[NB - 1] + 0;
    if (t == NB - 1) bucketBase[NB] = s[t];  // total kept edges
}

// ---- partition pass A2: scatter packed edges into bucket-partitioned array ----
// MUST iterate identically to A1 (same grid, same guards) so counts match bases.
__global__ __launch_bounds__(256) void k_partA2(const int* __restrict__ ei,
                                                const int* __restrict__ bucketBase,
                                                const int* __restrict__ blockBase,
                                                unsigned* __restrict__ part,
                                                const int* __restrict__ flags, int E, int N) {
    __shared__ int cur[NB];
    int t = threadIdx.x;
    if (t < NB) cur[t] = bucketBase[t] + blockBase[blockIdx.x * NB + t];
    __syncthreads();
    int w = flags[0];
    for (int e = blockIdx.x * 256 + t; e < E; e += PBLOCKS * 256) {
        int d = IG(ei, E + e, w);
        int s = IG(ei, e, w);
        if ((unsigned)d < (unsigned)N && (unsigned)s < (unsigned)N) {
            int slot = atomicAdd(&cur[d >> 9], 1);
            part[slot] = ((unsigned)(d & 511) << 16) | (unsigned)s;
        }
    }
}

// ---- partition pass B: one block per bucket -> rowptr, dinv, col (all LDS-local) ----
__global__ __launch_bounds__(256) void k_partB(const unsigned* __restrict__ part,
                                               const int* __restrict__ bucketBase,
                                               int* __restrict__ rowptr, float* __restrict__ dinv,
                                               int* __restrict__ col, int N) {
    __shared__ int hist[512];
    __shared__ int scn[512];
    __shared__ int pair[256];
    int b = blockIdx.x, t = threadIdx.x;
    int s0 = bucketBase[b], e0 = bucketBase[b + 1];
    hist[t] = 0; hist[t + 256] = 0;
    __syncthreads();
    for (int j = s0 + t; j < e0; j += 256)
        atomicAdd(&hist[part[j] >> 16], 1);
    __syncthreads();
    // exclusive scan over 512 via pair-sums
    int a0 = hist[2 * t], a1 = hist[2 * t + 1];
    int pv = a0 + a1;
    pair[t] = pv;
    __syncthreads();
    for (int off = 1; off < 256; off <<= 1) {
        int add = (t >= off) ? pair[t - off] : 0;
        __syncthreads();
        pair[t] += add;
        __syncthreads();
    }
    int pbase = pair[t] - pv;  // exclusive pair base
    scn[2 * t] = pbase;
    scn[2 * t + 1] = pbase + a0;
    __syncthreads();
#pragma unroll
    for (int hh = 0; hh < 2; ++hh) {
        int l = t + hh * 256;
        int node = b * 512 + l;
        if (node < N) {
            rowptr[node] = s0 + scn[l];
            dinv[node] = rsqrtf((float)(hist[l] + 1));  // +1 self loop
        }
    }
    if (b == 0 && t == 0) rowptr[N] = bucketBase[NB];
    // reuse scn as cursors (already = local base)
    __syncthreads();
    for (int j = s0 + t; j < e0; j += 256) {
        unsigned p = part[j];
        int pos = s0 + atomicAdd(&scn[p >> 16], 1);
        col[pos] = (int)(p & 0xFFFFu);
    }
}

// ---- merged conversions: xs8 = fp8(x*dinv), w1t = W1^T, w2t = W2^T, gstart bounds ----
#define CVTX_BLOCKS 6250   // N*IN_F/4 / 256
#define CVT1_BLOCKS 128    // IN_F*256 / 256
#define CVT2_BLOCKS 256    // HID*256 / 256
#define GB_BLOCKS   196    // ceil((N+1)/256) graph-boundary segment
__global__ __launch_bounds__(256) void k_cvt(const void* __restrict__ x, const float* __restrict__ dinv,
                                             unsigned char* __restrict__ xs8,
                                             const void* __restrict__ W1, unsigned short* __restrict__ w1t,
                                             const void* __restrict__ W2, unsigned short* __restrict__ w2t,
                                             const int* __restrict__ batch, int* __restrict__ gstart,
                                             const int* __restrict__ flags) {
    int b = blockIdx.x;
    int fb = flags[1];
    if (b < CVTX_BLOCKS) {
        int gid = b * 256 + threadIdx.x;
        int row = gid >> 5;  // 32 4-elem chunks per 128-feat row
        float d = dinv[row];
        float vx, vy, vz, vw;
        if (fb) {
            ushort4 v = ((const ushort4*)x)[gid];
            vx = b2f(v.x); vy = b2f(v.y); vz = b2f(v.z); vw = b2f(v.w);
        } else {
            float4 v = ((const float4*)x)[gid];
            vx = v.x; vy = v.y; vz = v.z; vw = v.w;
        }
        ((unsigned*)xs8)[gid] = pk4_fp8(vx * d, vy * d, vz * d, vw * d);
    } else if (b < CVTX_BLOCKS + CVT1_BLOCKS) {
        int i = (b - CVTX_BLOCKS) * 256 + threadIdx.x;
        int n = i >> 7, k = i & 127;
        w1t[i] = f2b(LF(W1, k * 256 + n, fb));
    } else if (b < CVTX_BLOCKS + CVT1_BLOCKS + CVT2_BLOCKS) {
        int i = (b - CVTX_BLOCKS - CVT1_BLOCKS) * 256 + threadIdx.x;
        int n = i >> 8, k = i & 255;
        w2t[i] = f2b(LF(W2, k * 256 + n, fb));
    } else {
        int i = (b - CVTX_BLOCKS - CVT1_BLOCKS - CVT2_BLOCKS) * 256 + threadIdx.x;
        if (i <= N_NODES) {
            int w = flags[0];
            int prev = (i == 0) ? -1 : IG(batch, i - 1, w);
            int cur  = (i == N_NODES) ? N_GRAPH : IG(batch, i, w);
            if (prev < -1) prev = -1;
            if (cur > N_GRAPH) cur = N_GRAPH;
            for (int g = prev + 1; g <= cur; ++g)
                if (g >= 0 && g <= N_GRAPH) gstart[g] = i;
        }
    }
}

// ---- fused gather + 2-layer GCN GEMM: per 64-row block ----
// stage0: GATHER aggX tile directly from xs8 (fp8) via CSR — the aggX global
// round-trip (12.8 MB write + 12.8 MB read, r9's k_agg2) is deleted; sums are
// f32 then f2b, bit-identical to the old agg2->aggX->LDS path.
// phase1 (K=128): H1 = relu((A@W1)*dinv+b1) -> LDS bf16 [64][264].
// phase2 (K=256): A from LDS H1, B2 from L2; fp8 out via LDS-transpose epilogue.
// XW2s8 must NOT alias xs8 (gather reads xs8 while writing XW2s8).
__global__ __launch_bounds__(256) void k_gcn2l(const unsigned char* __restrict__ XS,
                                               const int* __restrict__ rowptr,
                                               const int* __restrict__ col,
                                               const unsigned short* __restrict__ B1t,
                                               const unsigned short* __restrict__ B2t,
                                               unsigned char* __restrict__ C8, int M,
                                               const float* __restrict__ dinv,
                                               const void* __restrict__ bias1,
                                               const int* __restrict__ flags) {
    __shared__ unsigned short As1[64 * 136];  // 17.4 KB agg tile (128 cols); reused as fp8 C-stage
    __shared__ unsigned short Hs[64 * 264];   // 33.8 KB H1 tile (256 cols)
    int t = threadIdx.x;
    int lane = t & 63;
    int w = t >> 6;               // wave -> 16-node gather group / 64-col GEMM slice
    int bm = blockIdx.x * 64;
    int l15 = lane & 15, quad = lane >> 4;
    int fb = flags[1];
    int fo = lane * 2;            // 2 features per lane in the gather

    // ---- stage 0: gather 16 nodes per wave (lane = 2 features, f32 sum -> bf16)
    for (int q = 0; q < 16; ++q) {
        int i = bm + w * 16 + q;
        ushort2 o;
        if (i < M) {
            unsigned sv = *(const unsigned short*)&XS[(size_t)i * 128 + fo];
            f32x2 a = cvt2lo(sv);
            int s = rowptr[i], e = rowptr[i + 1];
            int j = s;
            while (j + 16 <= e) {
                unsigned v[16];
#pragma unroll
                for (int p = 0; p < 16; ++p)
                    v[p] = *(const unsigned short*)&XS[(size_t)col[j + p] * 128 + fo];
#pragma unroll
                for (int p = 0; p < 16; ++p) a += cvt2lo(v[p]);
                j += 16;
            }
            if (j + 8 <= e) {
                unsigned v[8];
#pragma unroll
                for (int p = 0; p < 8; ++p)
                    v[p] = *(const unsigned short*)&XS[(size_t)col[j + p] * 128 + fo];
#pragma unroll
                for (int p = 0; p < 8; ++p) a += cvt2lo(v[p]);
                j += 8;
            }
            if (j + 4 <= e) {
                unsigned v[4];
#pragma unroll
                for (int p = 0; p < 4; ++p)
                    v[p] = *(const unsigned short*)&XS[(size_t)col[j + p] * 128 + fo];
#pragma unroll
                for (int p = 0; p < 4; ++p) a += cvt2lo(v[p]);
                j += 4;
            }
            for (; j < e; ++j)
                a += cvt2lo(*(const unsigned short*)&XS[(size_t)col[j] * 128 + fo]);
            o.x = f2b(a[0]); o.y = f2b(a[1]);
        } else {
            o.x = 0; o.y = 0;
        }
        *(ushort2*)&As1[(w * 16 + q) * 136 + fo] = o;
    }
    __syncthreads();

    f32x4 acc[4][4];
#pragma unroll
    for (int ar = 0; ar < 4; ++ar)
#pragma unroll
        for (int tt = 0; tt < 4; ++tt) acc[ar][tt] = (f32x4){0.f, 0.f, 0.f, 0.f};

    // ---- phase 1: K=128 (A from LDS, B1 from L2)
#pragma unroll
    for (int ks = 0; ks < 4; ++ks) {
        short8 a[4], b[4];
#pragma unroll
        for (int ar = 0; ar < 4; ++ar)
            a[ar] = *(const short8*)&As1[(ar * 16 + l15) * 136 + ks * 32 + quad * 8];
#pragma unroll
        for (int tt = 0; tt < 4; ++tt)
            b[tt] = *(const short8*)&B1t[(size_t)(w * 64 + tt * 16 + l15) * 128 + ks * 32 + quad * 8];
#pragma unroll
        for (int tt = 0; tt < 4; ++tt)
#pragma unroll
            for (int ar = 0; ar < 4; ++ar)
                acc[ar][tt] = __builtin_amdgcn_mfma_f32_16x16x32_bf16(b[tt], a[ar], acc[ar][tt], 0, 0, 0);
    }

    float drow[4];
#pragma unroll
    for (int ar = 0; ar < 4; ++ar) {
        int row = bm + ar * 16 + l15;
        drow[ar] = (row < M) ? dinv[row] : 1.f;
    }
    // phase-1 epilogue: H1 = relu(acc*dinv + b1) -> bf16 LDS tile
#pragma unroll
    for (int tt = 0; tt < 4; ++tt) {
        int colb = w * 64 + tt * 16 + quad * 4;
        float bc[4];
#pragma unroll
        for (int rr = 0; rr < 4; ++rr) bc[rr] = LF(bias1, colb + rr, fb);
#pragma unroll
        for (int ar = 0; ar < 4; ++ar) {
            ushort4 o;
            o.x = f2b(fmaxf(fmaf(acc[ar][tt][0], drow[ar], bc[0]), 0.f));
            o.y = f2b(fmaxf(fmaf(acc[ar][tt][1], drow[ar], bc[1]), 0.f));
            o.z = f2b(fmaxf(fmaf(acc[ar][tt][2], drow[ar], bc[2]), 0.f));
            o.w = f2b(fmaxf(fmaf(acc[ar][tt][3], drow[ar], bc[3]), 0.f));
            *(ushort4*)&Hs[(ar * 16 + l15) * 264 + colb] = o;
            acc[ar][tt] = (f32x4){0.f, 0.f, 0.f, 0.f};   // re-init for phase 2
        }
    }
    __syncthreads();   // H1 tile complete (all waves' column slices)

    // ---- phase 2: K=256 (A from LDS H1 tile, B2 from L2)
#pragma unroll
    for (int ks = 0; ks < 8; ++ks) {
        short8 a[4], b[4];
#pragma unroll
        for (int ar = 0; ar < 4; ++ar)
            a[ar] = *(const short8*)&Hs[(ar * 16 + l15) * 264 + ks * 32 + quad * 8];
#pragma unroll
        for (int tt = 0; tt < 4; ++tt)
            b[tt] = *(const short8*)&B2t[(size_t)(w * 64 + tt * 16 + l15) * 256 + ks * 32 + quad * 8];
#pragma unroll
        for (int tt = 0; tt < 4; ++tt)
#pragma unroll
            for (int ar = 0; ar < 4; ++ar)
                acc[ar][tt] = __builtin_amdgcn_mfma_f32_16x16x32_bf16(b[tt], a[ar], acc[ar][tt], 0, 0, 0);
    }

    // phase-2 epilogue: fp8(acc*dinv) via LDS transpose (As1 region dead since phase 1)
    unsigned* Cs = (unsigned*)As1;   // row stride 68 dwords (272 B, 16B-aligned)
    __syncthreads();                 // all phase-1 LDS reads done before overwrite
#pragma unroll
    for (int tt = 0; tt < 4; ++tt) {
#pragma unroll
        for (int ar = 0; ar < 4; ++ar) {
            float v0 = acc[ar][tt][0] * drow[ar];
            float v1 = acc[ar][tt][1] * drow[ar];
            float v2 = acc[ar][tt][2] * drow[ar];
            float v3 = acc[ar][tt][3] * drow[ar];
            Cs[(ar * 16 + l15) * 68 + w * 16 + tt * 4 + quad] = pk4_fp8(v0, v1, v2, v3);
        }
    }
    __syncthreads();
    int r = t >> 2, h = t & 3;       // 64 rows x 4 chunks of 64 B
    if (bm + r < M) {
        const unsigned* src = Cs + r * 68 + h * 16;
        uint4* dst = (uint4*)&C8[(size_t)(bm + r) * 256 + h * 64];
#pragma unroll
        for (int j = 0; j < 4; ++j) dst[j] = *(const uint4*)(src + j * 4);
    }
}

// ---- agg over 256-feat fp8 rows with scale+bias epilogue (bf16 out) ----
__global__ __launch_bounds__(256) void k_agg4(const unsigned char* __restrict__ XW,
                                              const int* __restrict__ rowptr, const int* __restrict__ col,
                                              const float* __restrict__ dinv, const void* __restrict__ bias,
                                              const int* __restrict__ flags,
                                              unsigned short* __restrict__ Hout, int N) {
    int lane = threadIdx.x & 63;
    int i = (blockIdx.x * 256 + threadIdx.x) >> 6;
    if (i >= N) return;
    int fo = lane * 4;
    unsigned sv = *(const unsigned*)&XW[(size_t)i * 256 + fo];
    f32x2 a01 = cvt2lo(sv), a23 = cvt2hi(sv);
    int s = rowptr[i], e = rowptr[i + 1];
    int j = s;
    while (j + 16 <= e) {
        unsigned v[16];
#pragma unroll
        for (int q = 0; q < 16; ++q)
            v[q] = *(const unsigned*)&XW[(size_t)col[j + q] * 256 + fo];
#pragma unroll
        for (int q = 0; q < 16; ++q) { a01 += cvt2lo(v[q]); a23 += cvt2hi(v[q]); }
        j += 16;
    }
    if (j + 8 <= e) {
        unsigned v[8];
#pragma unroll
        for (int q = 0; q < 8; ++q)
            v[q] = *(const unsigned*)&XW[(size_t)col[j + q] * 256 + fo];
#pragma unroll
        for (int q = 0; q < 8; ++q) { a01 += cvt2lo(v[q]); a23 += cvt2hi(v[q]); }
        j += 8;
    }
    if (j + 4 <= e) {
        unsigned v[4];
#pragma unroll
        for (int q = 0; q < 4; ++q)
            v[q] = *(const unsigned*)&XW[(size_t)col[j + q] * 256 + fo];
#pragma unroll
        for (int q = 0; q < 4; ++q) { a01 += cvt2lo(v[q]); a23 += cvt2hi(v[q]); }
        j += 4;
    }
    for (; j < e; ++j) {
        unsigned v = *(const unsigned*)&XW[(size_t)col[j] * 256 + fo];
        a01 += cvt2lo(v); a23 += cvt2hi(v);
    }
    int fb = flags[1];
    float di = dinv[i];
    float bx = LF(bias, fo + 0, fb), by = LF(bias, fo + 1, fb);
    float bz = LF(bias, fo + 2, fb), bw = LF(bias, fo + 3, fb);
    ushort4 o;
    o.x = f2b(fmaf(a01[0], di, bx)); o.y = f2b(fmaf(a01[1], di, by));
    o.z = f2b(fmaf(a23[0], di, bz)); o.w = f2b(fmaf(a23[1], di, bw));
    *(ushort4*)&Hout[(size_t)i * 256 + fo] = o;
}

// ---- segment-mean pool + classifier, one block per graph ----
__global__ __launch_bounds__(256) void k_poolfinal(const unsigned short* __restrict__ H2,
                                                   const int* __restrict__ gstart,
                                                   const void* __restrict__ Wlin,
                                                   const void* __restrict__ blin,
                                                   const int* __restrict__ flags,
                                                   void* __restrict__ outv) {
    __shared__ float red[4][256];
    __shared__ float p[256];
    int g = blockIdx.x, t = threadIdx.x;
    int sub = t >> 6, lane = t & 63;
    int s = gstart[g], e = gstart[g + 1];
    int cnt = e - s;
    float ax = 0.f, ay = 0.f, az = 0.f, aw = 0.f;
    for (int i = s + sub; i < e; i += 4) {
        ushort4 v = *(const ushort4*)&H2[(size_t)i * 256 + lane * 4];
        ax += b2f(v.x); ay += b2f(v.y); az += b2f(v.z); aw += b2f(v.w);
    }
    red[sub][lane * 4 + 0] = ax;
    red[sub][lane * 4 + 1] = ay;
    red[sub][lane * 4 + 2] = az;
    red[sub][lane * 4 + 3] = aw;
    __syncthreads();
    float inv = 1.f / fmaxf((float)cnt, 1.f);
    p[t] = (red[0][t] + red[1][t] + red[2][t] + red[3][t]) * inv;
    __syncthreads();
    int fb = flags[1];
    if (t < N_CLS) {
        float sum = LF(blin, t, fb);
        for (int f = 0; f < HID; ++f) sum = fmaf(p[f], LF(Wlin, f * N_CLS + t, fb), sum);
        if (fb) ((bf16*)outv)[g * N_CLS + t] = __float2bfloat16(sum);
        else    ((float*)outv)[g * N_CLS + t] = sum;
    }
}

extern "C" void kernel_launch(void* const* d_in, const int* in_sizes, int n_in,
                              void* d_out, int out_size, void* d_ws, size_t ws_size,
                              hipStream_t stream) {
    (void)n_in; (void)ws_size; (void)in_sizes; (void)out_size;
    const void* x     = d_in[0];
    const int*  ei    = (const int*)d_in[1];
    const int*  batch = (const int*)d_in[2];
    const void* W1    = d_in[3];
    const void* b1    = d_in[4];
    const void* W2    = d_in[5];
    const void* b2    = d_in[6];
    const void* Wl    = d_in[7];
    const void* bl    = d_in[8];

    const int N = N_NODES, E = N_EDGES, F = IN_F, H = HID, G = N_GRAPH;

    char* ws = (char*)d_ws;
    size_t off = 0;
    auto alloc = [&](size_t bytes) -> void* {
        void* p = ws + off;
        off += (bytes + 511) & ~(size_t)511;
        return p;
    };
    unsigned char*  xs8  = (unsigned char*)alloc((size_t)N * F);       // fp8 prescaled x (6.4 MB)
    unsigned char*  XW2s8 = (unsigned char*)alloc((size_t)N * H);      // fp8 XW2 (12.8 MB) — must NOT alias xs8 (gcn2l reads xs8 while writing this)
    unsigned short* H2   = (unsigned short*)alloc((size_t)N * H * 2);  // bf16 (25.6 MB)
    unsigned short* w1t  = (unsigned short*)alloc((size_t)H * F * 2);
    unsigned short* w2t  = (unsigned short*)alloc((size_t)H * H * 2);
    int*   bucketCnt = (int*)alloc((size_t)NB * 16 * 4);   // zero region (padded: 1 line/bucket)
    int*   bucketBase = (int*)alloc((size_t)(NB + 1) * 4);
    int*   blockBase = (int*)alloc((size_t)PBLOCKS * NB * 4);
    unsigned* part  = (unsigned*)alloc((size_t)E * 4);     // packed (d&511)<<16 | s
    int*   gstart  = (int*)alloc((size_t)(G + 1) * 4);
    float* dinv    = (float*)alloc((size_t)N * 4);
    int*   rowptr  = (int*)alloc((size_t)(N + 1) * 4);
    int*   flags   = (int*)alloc(512);
    int*   col     = (int*)alloc((size_t)E * 4);
    size_t zero_bytes = (size_t)NB * 16 * 4;

    hipMemsetAsync(bucketCnt, 0, zero_bytes, stream);

    k_detect<<<1, 256, 0, stream>>>(ei, (const unsigned short*)x, flags);
    k_partA1<<<PBLOCKS, 256, 0, stream>>>(ei, bucketCnt, blockBase, flags, E, N);
    k_bscan<<<1, 128, 0, stream>>>(bucketCnt, bucketBase);
    k_partA2<<<PBLOCKS, 256, 0, stream>>>(ei, bucketBase, blockBase, part, flags, E, N);
    k_partB<<<NB, 256, 0, stream>>>(part, bucketBase, rowptr, dinv, col, N);

    // merged conversions (fp8 prescaled x + transposed weights + graph bounds)
    k_cvt<<<CVTX_BLOCKS + CVT1_BLOCKS + CVT2_BLOCKS + GB_BLOCKS, 256, 0, stream>>>(
        x, dinv, xs8, W1, w1t, W2, w2t, batch, gstart, flags);

    int g64 = (N + 63) >> 6;   // 782 64-row blocks
    int nbAgg = (N + 3) / 4;

    // fused gather + 2-layer GEMM (aggX round-trip deleted), then layer-2 aggregate
    k_gcn2l<<<g64, 256, 0, stream>>>(xs8, rowptr, col, w1t, w2t, XW2s8, N, dinv, b1, flags);
    k_agg4<<<nbAgg, 256, 0, stream>>>(XW2s8, rowptr, col, dinv, b2, flags, H2, N);
    // pool + classify (merged)
    k_poolfinal<<<G, 256, 0, stream>>>(H2, gstart, Wl, bl, flags, d_out);
}

// Round 12
// 255.246 us; speedup vs baseline: 1.1671x; 1.1671x over previous
//
#include <hip/hip_runtime.h>
#include <hip/hip_bf16.h>

typedef __hip_bfloat16 bf16;
typedef __attribute__((ext_vector_type(8))) short short8;
typedef __attribute__((ext_vector_type(4))) float f32x4;
typedef __attribute__((ext_vector_type(2))) float f32x2;

// ---- problem constants (fixed by reference file) ----
#define N_NODES 50000
#define N_EDGES 800000
#define IN_F    128
#define HID     256
#define N_CLS   10
#define N_GRAPH 256

// radix-partition CSR build
#define NB 98          // buckets = ceil(N / 512), bucket = d >> 9
#define PBLOCKS 256    // partition grid (A1/A2 must match exactly)

// flags[0] = ints are int64 (read low words), flags[1] = floats are bf16
__device__ __forceinline__ int IG(const int* __restrict__ p, int i, int w) {
    return w ? p[2 * i] : p[i];
}
__device__ __forceinline__ float LF(const void* __restrict__ p, int i, int isbf) {
    return isbf ? __bfloat162float(((const bf16*)p)[i]) : ((const float*)p)[i];
}
__device__ __forceinline__ float b2f(unsigned short h) {
    union { unsigned u; float f; } c; c.u = ((unsigned)h) << 16; return c.f;
}
__device__ __forceinline__ unsigned short f2b(float x) {
    bf16 h = __float2bfloat16(x);
    union { bf16 b; unsigned short u; } c; c.b = h; return c.u;
}
// fp8 e4m3 byte -> float scaled by 2^-120 (fallback decode path)
__device__ __forceinline__ float f8s(unsigned b) {
    union { unsigned u; float f; } c;
    c.u = ((b & 0x80u) << 24) | ((b & 0x7Fu) << 20);
    return c.f;
}
#define F8SCALE 0x1p120f
// float -> OCP fp8 e4m3 (RTNE via bf16 intermediate; FTZ below subnormal range)
__device__ __forceinline__ unsigned f2fp8(float x) {
    unsigned short h = f2b(x * 0x1p-120f);
    unsigned s = ((unsigned)h >> 8) & 0x80u;
    unsigned mag = (unsigned)h & 0x7FFFu;
    unsigned r = (mag + 7u + ((mag >> 4) & 1u)) >> 4;
    if (r > 0x7Eu) r = 0x7Eu;
    return s | r;
}

#if defined(__has_builtin)
#if __has_builtin(__builtin_amdgcn_cvt_pk_f32_fp8)
#define HW_FP8 1
#endif
#if __has_builtin(__builtin_amdgcn_cvt_pk_fp8_f32)
#define HW_FP8E 1
#endif
#endif

// decode 2 fp8 bytes (low or high half of a dword) -> float2, true magnitudes
__device__ __forceinline__ f32x2 cvt2lo(unsigned v) {
#ifdef HW_FP8
    return __builtin_amdgcn_cvt_pk_f32_fp8((int)v, false);
#else
    f32x2 r; r[0] = f8s(v & 0xFF) * F8SCALE; r[1] = f8s((v >> 8) & 0xFF) * F8SCALE; return r;
#endif
}
__device__ __forceinline__ f32x2 cvt2hi(unsigned v) {
#ifdef HW_FP8
    return __builtin_amdgcn_cvt_pk_f32_fp8((int)v, true);
#else
    f32x2 r; r[0] = f8s((v >> 16) & 0xFF) * F8SCALE; r[1] = f8s(v >> 24) * F8SCALE; return r;
#endif
}
// pack 4 floats -> 4 fp8 bytes (HW packed cvt when available)
__device__ __forceinline__ unsigned pk4_fp8(float v0, float v1, float v2, float v3) {
#ifdef HW_FP8E
    int o = __builtin_amdgcn_cvt_pk_fp8_f32(v0, v1, 0, false);
    o = __builtin_amdgcn_cvt_pk_fp8_f32(v2, v3, o, true);
    return (unsigned)o;
#else
    return f2fp8(v0) | (f2fp8(v1) << 8) | (f2fp8(v2) << 16) | (f2fp8(v3) << 24);
#endif
}

// ---- combined dtype detectors (1 block) ----
__global__ __launch_bounds__(256) void k_detect(const int* __restrict__ ei,
                                                const unsigned short* __restrict__ x,
                                                int* __restrict__ flags) {
    __shared__ int nz, cnt;
    if (threadIdx.x == 0) { nz = 0; cnt = 0; }
    __syncthreads();
    int found = 0, c = 0;
    for (int s = 0; s < 4; ++s) {
        int idx = 2 * (threadIdx.x * 4 + s) + 1;
        if (ei[idx] != 0) found = 1;
    }
    for (int s = 0; s < 8; ++s) {
        unsigned short h = x[threadIdx.x * 8 + s];
        int e = (h >> 7) & 0xFF;
        if (e >= 110 && e <= 135) c++;
    }
    if (found) atomicAdd(&nz, 1);
    atomicAdd(&cnt, c);
    __syncthreads();
    if (threadIdx.x == 0) {
        flags[0] = (nz == 0) ? 1 : 0;
        flags[1] = (cnt > 1536) ? 1 : 0;
    }
}

// ---- partition pass A1: LDS bucket histogram -> reserve global bases ----
// bucketCnt is padded: count for bucket q lives at bucketCnt[q*16] (one 64B line each)
__global__ __launch_bounds__(256) void k_partA1(const int* __restrict__ ei, int* __restrict__ bucketCnt,
                                                int* __restrict__ blockBase, const int* __restrict__ flags,
                                                int E, int N) {
    __shared__ int h[NB];
    int t = threadIdx.x;
    if (t < NB) h[t] = 0;
    __syncthreads();
    int w = flags[0];
    for (int e = blockIdx.x * 256 + t; e < E; e += PBLOCKS * 256) {
        int d = IG(ei, E + e, w);
        int s = IG(ei, e, w);
        if ((unsigned)d < (unsigned)N && (unsigned)s < (unsigned)N)
            atomicAdd(&h[d >> 9], 1);
    }
    __syncthreads();
    if (t < NB)
        blockBase[blockIdx.x * NB + t] = atomicAdd(&bucketCnt[t * 16], h[t]);
}

// ---- 1-block exclusive scan of bucket counts ----
__global__ __launch_bounds__(128) void k_bscan(const int* __restrict__ bucketCnt,
                                               int* __restrict__ bucketBase) {
    __shared__ int s[128];
    int t = threadIdx.x;
    int v = (t < NB) ? bucketCnt[t * 16] : 0;
    s[t] = v;
    __syncthreads();
    for (int off = 1; off < 128; off <<= 1) {
        int add = (t >= off) ? s[t - off] : 0;
        __syncthreads();
        s[t] += add;
        __syncthreads();
    }
    if (t <= NB) bucketBase[t] = (t < NB) ? (s[t] - v) : s[NB - 1] + 0;
    if (t == NB - 1) bucketBase[NB] = s[t];  // total kept edges
}

// ---- partition pass A2: scatter packed edges into bucket-partitioned array ----
// MUST iterate identically to A1 (same grid, same guards) so counts match bases.
__global__ __launch_bounds__(256) void k_partA2(const int* __restrict__ ei,
                                                const int* __restrict__ bucketBase,
                                                const int* __restrict__ blockBase,
                                                unsigned* __restrict__ part,
                                                const int* __restrict__ flags, int E, int N) {
    __shared__ int cur[NB];
    int t = threadIdx.x;
    if (t < NB) cur[t] = bucketBase[t] + blockBase[blockIdx.x * NB + t];
    __syncthreads();
    int w = flags[0];
    for (int e = blockIdx.x * 256 + t; e < E; e += PBLOCKS * 256) {
        int d = IG(ei, E + e, w);
        int s = IG(ei, e, w);
        if ((unsigned)d < (unsigned)N && (unsigned)s < (unsigned)N) {
            int slot = atomicAdd(&cur[d >> 9], 1);
            part[slot] = ((unsigned)(d & 511) << 16) | (unsigned)s;
        }
    }
}

// ---- partition pass B: one block per bucket -> rowptr, dinv, col (all LDS-local) ----
__global__ __launch_bounds__(256) void k_partB(const unsigned* __restrict__ part,
                                               const int* __restrict__ bucketBase,
                                               int* __restrict__ rowptr, float* __restrict__ dinv,
                                               int* __restrict__ col, int N) {
    __shared__ int hist[512];
    __shared__ int scn[512];
    __shared__ int pair[256];
    int b = blockIdx.x, t = threadIdx.x;
    int s0 = bucketBase[b], e0 = bucketBase[b + 1];
    hist[t] = 0; hist[t + 256] = 0;
    __syncthreads();
    for (int j = s0 + t; j < e0; j += 256)
        atomicAdd(&hist[part[j] >> 16], 1);
    __syncthreads();
    // exclusive scan over 512 via pair-sums
    int a0 = hist[2 * t], a1 = hist[2 * t + 1];
    int pv = a0 + a1;
    pair[t] = pv;
    __syncthreads();
    for (int off = 1; off < 256; off <<= 1) {
        int add = (t >= off) ? pair[t - off] : 0;
        __syncthreads();
        pair[t] += add;
        __syncthreads();
    }
    int pbase = pair[t] - pv;  // exclusive pair base
    scn[2 * t] = pbase;
    scn[2 * t + 1] = pbase + a0;
    __syncthreads();
#pragma unroll
    for (int hh = 0; hh < 2; ++hh) {
        int l = t + hh * 256;
        int node = b * 512 + l;
        if (node < N) {
            rowptr[node] = s0 + scn[l];
            dinv[node] = rsqrtf((float)(hist[l] + 1));  // +1 self loop
        }
    }
    if (b == 0 && t == 0) rowptr[N] = bucketBase[NB];
    // reuse scn as cursors (already = local base)
    __syncthreads();
    for (int j = s0 + t; j < e0; j += 256) {
        unsigned p = part[j];
        int pos = s0 + atomicAdd(&scn[p >> 16], 1);
        col[pos] = (int)(p & 0xFFFFu);
    }
}

// ---- merged conversions: xs8 = fp8(x*dinv), w1t = W1^T, w2t = W2^T, gstart bounds ----
#define CVTX_BLOCKS 6250   // N*IN_F/4 / 256
#define CVT1_BLOCKS 128    // IN_F*256 / 256
#define CVT2_BLOCKS 256    // HID*256 / 256
#define GB_BLOCKS   196    // ceil((N+1)/256) graph-boundary segment
__global__ __launch_bounds__(256) void k_cvt(const void* __restrict__ x, const float* __restrict__ dinv,
                                             unsigned char* __restrict__ xs8,
                                             const void* __restrict__ W1, unsigned short* __restrict__ w1t,
                                             const void* __restrict__ W2, unsigned short* __restrict__ w2t,
                                             const int* __restrict__ batch, int* __restrict__ gstart,
                                             const int* __restrict__ flags) {
    int b = blockIdx.x;
    int fb = flags[1];
    if (b < CVTX_BLOCKS) {
        int gid = b * 256 + threadIdx.x;
        int row = gid >> 5;  // 32 4-elem chunks per 128-feat row
        float d = dinv[row];
        float vx, vy, vz, vw;
        if (fb) {
            ushort4 v = ((const ushort4*)x)[gid];
            vx = b2f(v.x); vy = b2f(v.y); vz = b2f(v.z); vw = b2f(v.w);
        } else {
            float4 v = ((const float4*)x)[gid];
            vx = v.x; vy = v.y; vz = v.z; vw = v.w;
        }
        ((unsigned*)xs8)[gid] = pk4_fp8(vx * d, vy * d, vz * d, vw * d);
    } else if (b < CVTX_BLOCKS + CVT1_BLOCKS) {
        int i = (b - CVTX_BLOCKS) * 256 + threadIdx.x;
        int n = i >> 7, k = i & 127;
        w1t[i] = f2b(LF(W1, k * 256 + n, fb));
    } else if (b < CVTX_BLOCKS + CVT1_BLOCKS + CVT2_BLOCKS) {
        int i = (b - CVTX_BLOCKS - CVT1_BLOCKS) * 256 + threadIdx.x;
        int n = i >> 8, k = i & 255;
        w2t[i] = f2b(LF(W2, k * 256 + n, fb));
    } else {
        int i = (b - CVTX_BLOCKS - CVT1_BLOCKS - CVT2_BLOCKS) * 256 + threadIdx.x;
        if (i <= N_NODES) {
            int w = flags[0];
            int prev = (i == 0) ? -1 : IG(batch, i - 1, w);
            int cur  = (i == N_NODES) ? N_GRAPH : IG(batch, i, w);
            if (prev < -1) prev = -1;
            if (cur > N_GRAPH) cur = N_GRAPH;
            for (int g = prev + 1; g <= cur; ++g)
                if (g >= 0 && g <= N_GRAPH) gstart[g] = i;
        }
    }
}

// ---- fused 2-layer GCN GEMM: per 64-row block, both layers, H1 never leaves LDS ----
// (r9-validated) stage0: stage aggX[64x128] -> LDS. phase1 (K=128): H1 tile =
// relu((A@W1)*dinv + b1) -> LDS bf16 [64][264]. phase2 (K=256): A from the LDS
// H1 tile, B2 (128KB, L2-resident) from global; fp8 out via LDS-transpose
// epilogue. r11 lesson: do NOT pull the CSR gather in here — gather needs
// 50K-wave parallelism (dedicated k_agg2), the fused version cost +60us.
__global__ __launch_bounds__(256) void k_gcn2l(const unsigned short* __restrict__ A,
                                               const unsigned short* __restrict__ B1t,
                                               const unsigned short* __restrict__ B2t,
                                               unsigned char* __restrict__ C8, int M,
                                               const float* __restrict__ dinv,
                                               const void* __restrict__ bias1,
                                               const int* __restrict__ flags) {
    __shared__ unsigned short As1[64 * 136];  // 17.4 KB aggX tile (128 cols); reused as fp8 C-stage
    __shared__ unsigned short Hs[64 * 264];   // 33.8 KB H1 tile (256 cols, 528B stride -> 2-way banks)
    int t = threadIdx.x;
    int lane = t & 63;
    int w = t >> 6;               // wave -> 64-col slice
    int bm = blockIdx.x * 64;
    int l15 = lane & 15, quad = lane >> 4;
    int fb = flags[1];

    // ---- stage aggX tile (rows >= M read adjacent workspace; discarded later)
    {
        const uint4* src = (const uint4*)&A[(size_t)bm * 128];
#pragma unroll
        for (int j = 0; j < 4; ++j) {
            int f = t + j * 256;           // uint4 index 0..1023 (16 per row)
            int row = f >> 4, cu = f & 15;
            *(uint4*)&As1[row * 136 + cu * 8] = src[(size_t)row * 16 + cu];
        }
    }
    __syncthreads();

    f32x4 acc[4][4];
#pragma unroll
    for (int ar = 0; ar < 4; ++ar)
#pragma unroll
        for (int tt = 0; tt < 4; ++tt) acc[ar][tt] = (f32x4){0.f, 0.f, 0.f, 0.f};

    // ---- phase 1: K=128 (A from LDS, B1 from L2)
#pragma unroll
    for (int ks = 0; ks < 4; ++ks) {
        short8 a[4], b[4];
#pragma unroll
        for (int ar = 0; ar < 4; ++ar)
            a[ar] = *(const short8*)&As1[(ar * 16 + l15) * 136 + ks * 32 + quad * 8];
#pragma unroll
        for (int tt = 0; tt < 4; ++tt)
            b[tt] = *(const short8*)&B1t[(size_t)(w * 64 + tt * 16 + l15) * 128 + ks * 32 + quad * 8];
#pragma unroll
        for (int tt = 0; tt < 4; ++tt)
#pragma unroll
            for (int ar = 0; ar < 4; ++ar)
                acc[ar][tt] = __builtin_amdgcn_mfma_f32_16x16x32_bf16(b[tt], a[ar], acc[ar][tt], 0, 0, 0);
    }

    float drow[4];
#pragma unroll
    for (int ar = 0; ar < 4; ++ar) {
        int row = bm + ar * 16 + l15;
        drow[ar] = (row < M) ? dinv[row] : 1.f;
    }
    // phase-1 epilogue: H1 = relu(acc*dinv + b1) -> bf16 LDS tile
#pragma unroll
    for (int tt = 0; tt < 4; ++tt) {
        int colb = w * 64 + tt * 16 + quad * 4;
        float bc[4];
#pragma unroll
        for (int rr = 0; rr < 4; ++rr) bc[rr] = LF(bias1, colb + rr, fb);
#pragma unroll
        for (int ar = 0; ar < 4; ++ar) {
            ushort4 o;
            o.x = f2b(fmaxf(fmaf(acc[ar][tt][0], drow[ar], bc[0]), 0.f));
            o.y = f2b(fmaxf(fmaf(acc[ar][tt][1], drow[ar], bc[1]), 0.f));
            o.z = f2b(fmaxf(fmaf(acc[ar][tt][2], drow[ar], bc[2]), 0.f));
            o.w = f2b(fmaxf(fmaf(acc[ar][tt][3], drow[ar], bc[3]), 0.f));
            *(ushort4*)&Hs[(ar * 16 + l15) * 264 + colb] = o;
            acc[ar][tt] = (f32x4){0.f, 0.f, 0.f, 0.f};   // re-init for phase 2
        }
    }
    __syncthreads();   // H1 tile complete (all waves' column slices)

    // ---- phase 2: K=256 (A from LDS H1 tile, B2 from L2)
#pragma unroll
    for (int ks = 0; ks < 8; ++ks) {
        short8 a[4], b[4];
#pragma unroll
        for (int ar = 0; ar < 4; ++ar)
            a[ar] = *(const short8*)&Hs[(ar * 16 + l15) * 264 + ks * 32 + quad * 8];
#pragma unroll
        for (int tt = 0; tt < 4; ++tt)
            b[tt] = *(const short8*)&B2t[(size_t)(w * 64 + tt * 16 + l15) * 256 + ks * 32 + quad * 8];
#pragma unroll
        for (int tt = 0; tt < 4; ++tt)
#pragma unroll
            for (int ar = 0; ar < 4; ++ar)
                acc[ar][tt] = __builtin_amdgcn_mfma_f32_16x16x32_bf16(b[tt], a[ar], acc[ar][tt], 0, 0, 0);
    }

    // phase-2 epilogue: fp8(acc*dinv) via LDS transpose (As1 region dead since phase 1)
    unsigned* Cs = (unsigned*)As1;   // row stride 68 dwords (272 B, 16B-aligned)
    __syncthreads();                 // all phase-1 LDS reads done before overwrite
#pragma unroll
    for (int tt = 0; tt < 4; ++tt) {
#pragma unroll
        for (int ar = 0; ar < 4; ++ar) {
            float v0 = acc[ar][tt][0] * drow[ar];
            float v1 = acc[ar][tt][1] * drow[ar];
            float v2 = acc[ar][tt][2] * drow[ar];
            float v3 = acc[ar][tt][3] * drow[ar];
            Cs[(ar * 16 + l15) * 68 + w * 16 + tt * 4 + quad] = pk4_fp8(v0, v1, v2, v3);
        }
    }
    __syncthreads();
    int r = t >> 2, h = t & 3;       // 64 rows x 4 chunks of 64 B
    if (bm + r < M) {
        const unsigned* src = Cs + r * 68 + h * 16;
        uint4* dst = (uint4*)&C8[(size_t)(bm + r) * 256 + h * 64];
#pragma unroll
        for (int j = 0; j < 4; ++j) dst[j] = *(const uint4*)(src + j * 4);
    }
}

// ---- agg over 128-feat fp8 rows, XCD-aligned block map (64-row groups) ----
// block j -> XCD j%8; map so 64-node group g = i>>6 is produced on XCD g%8,
// matching k_gcn2l's consumer placement (bx%8).
__global__ __launch_bounds__(256) void k_agg2(const unsigned char* __restrict__ XS,
                                              const int* __restrict__ rowptr, const int* __restrict__ col,
                                              unsigned short* __restrict__ Hout, int N) {
    int jb = blockIdx.x;
    int x8 = jb & 7, k = jb >> 3;
    int gIdx = k >> 4, win = k & 15;
    int node0 = (gIdx * 8 + x8) * 64 + win * 4;
    int lane = threadIdx.x & 63;
    int i = node0 + (threadIdx.x >> 6);
    if (i >= N) return;
    int fo = lane * 2;
    unsigned sv = *(const unsigned short*)&XS[(size_t)i * 128 + fo];
    f32x2 a = cvt2lo(sv);
    int s = rowptr[i], e = rowptr[i + 1];
    int j = s;
    while (j + 16 <= e) {
        unsigned v[16];
#pragma unroll
        for (int q = 0; q < 16; ++q)
            v[q] = *(const unsigned short*)&XS[(size_t)col[j + q] * 128 + fo];
#pragma unroll
        for (int q = 0; q < 16; ++q) a += cvt2lo(v[q]);
        j += 16;
    }
    if (j + 8 <= e) {
        unsigned v[8];
#pragma unroll
        for (int q = 0; q < 8; ++q)
            v[q] = *(const unsigned short*)&XS[(size_t)col[j + q] * 128 + fo];
#pragma unroll
        for (int q = 0; q < 8; ++q) a += cvt2lo(v[q]);
        j += 8;
    }
    if (j + 4 <= e) {
        unsigned v[4];
#pragma unroll
        for (int q = 0; q < 4; ++q)
            v[q] = *(const unsigned short*)&XS[(size_t)col[j + q] * 128 + fo];
#pragma unroll
        for (int q = 0; q < 4; ++q) a += cvt2lo(v[q]);
        j += 4;
    }
    for (; j < e; ++j)
        a += cvt2lo(*(const unsigned short*)&XS[(size_t)col[j] * 128 + fo]);
    ushort2 o;
    o.x = f2b(a[0]); o.y = f2b(a[1]);
    *(ushort2*)&Hout[(size_t)i * 128 + fo] = o;
}

// ---- agg over 256-feat fp8 rows with scale+bias epilogue (bf16 out) ----
__global__ __launch_bounds__(256) void k_agg4(const unsigned char* __restrict__ XW,
                                              const int* __restrict__ rowptr, const int* __restrict__ col,
                                              const float* __restrict__ dinv, const void* __restrict__ bias,
                                              const int* __restrict__ flags,
                                              unsigned short* __restrict__ Hout, int N) {
    int lane = threadIdx.x & 63;
    int i = (blockIdx.x * 256 + threadIdx.x) >> 6;
    if (i >= N) return;
    int fo = lane * 4;
    unsigned sv = *(const unsigned*)&XW[(size_t)i * 256 + fo];
    f32x2 a01 = cvt2lo(sv), a23 = cvt2hi(sv);
    int s = rowptr[i], e = rowptr[i + 1];
    int j = s;
    while (j + 16 <= e) {
        unsigned v[16];
#pragma unroll
        for (int q = 0; q < 16; ++q)
            v[q] = *(const unsigned*)&XW[(size_t)col[j + q] * 256 + fo];
#pragma unroll
        for (int q = 0; q < 16; ++q) { a01 += cvt2lo(v[q]); a23 += cvt2hi(v[q]); }
        j += 16;
    }
    if (j + 8 <= e) {
        unsigned v[8];
#pragma unroll
        for (int q = 0; q < 8; ++q)
            v[q] = *(const unsigned*)&XW[(size_t)col[j + q] * 256 + fo];
#pragma unroll
        for (int q = 0; q < 8; ++q) { a01 += cvt2lo(v[q]); a23 += cvt2hi(v[q]); }
        j += 8;
    }
    if (j + 4 <= e) {
        unsigned v[4];
#pragma unroll
        for (int q = 0; q < 4; ++q)
            v[q] = *(const unsigned*)&XW[(size_t)col[j + q] * 256 + fo];
#pragma unroll
        for (int q = 0; q < 4; ++q) { a01 += cvt2lo(v[q]); a23 += cvt2hi(v[q]); }
        j += 4;
    }
    for (; j < e; ++j) {
        unsigned v = *(const unsigned*)&XW[(size_t)col[j] * 256 + fo];
        a01 += cvt2lo(v); a23 += cvt2hi(v);
    }
    int fb = flags[1];
    float di = dinv[i];
    float bx = LF(bias, fo + 0, fb), by = LF(bias, fo + 1, fb);
    float bz = LF(bias, fo + 2, fb), bw = LF(bias, fo + 3, fb);
    ushort4 o;
    o.x = f2b(fmaf(a01[0], di, bx)); o.y = f2b(fmaf(a01[1], di, by));
    o.z = f2b(fmaf(a23[0], di, bz)); o.w = f2b(fmaf(a23[1], di, bw));
    *(ushort4*)&Hout[(size_t)i * 256 + fo] = o;
}

// ---- segment-mean pool + classifier, one block per graph (512 thr = 8 waves:
// halves the serial H2-read depth of the least-parallel kernel in the pipe) ----
__global__ __launch_bounds__(512) void k_poolfinal(const unsigned short* __restrict__ H2,
                                                   const int* __restrict__ gstart,
                                                   const void* __restrict__ Wlin,
                                                   const void* __restrict__ blin,
                                                   const int* __restrict__ flags,
                                                   void* __restrict__ outv) {
    __shared__ float red[8][256];
    __shared__ float p[256];
    int g = blockIdx.x, t = threadIdx.x;
    int sub = t >> 6, lane = t & 63;
    int s = gstart[g], e = gstart[g + 1];
    int cnt = e - s;
    float ax = 0.f, ay = 0.f, az = 0.f, aw = 0.f;
    for (int i = s + sub; i < e; i += 8) {
        ushort4 v = *(const ushort4*)&H2[(size_t)i * 256 + lane * 4];
        ax += b2f(v.x); ay += b2f(v.y); az += b2f(v.z); aw += b2f(v.w);
    }
    red[sub][lane * 4 + 0] = ax;
    red[sub][lane * 4 + 1] = ay;
    red[sub][lane * 4 + 2] = az;
    red[sub][lane * 4 + 3] = aw;
    __syncthreads();
    if (t < 256) {
        float inv = 1.f / fmaxf((float)cnt, 1.f);
        float sum8 = 0.f;
#pragma unroll
        for (int q = 0; q < 8; ++q) sum8 += red[q][t];
        p[t] = sum8 * inv;
    }
    __syncthreads();
    int fb = flags[1];
    if (t < N_CLS) {
        float sum = LF(blin, t, fb);
        for (int f = 0; f < HID; ++f) sum = fmaf(p[f], LF(Wlin, f * N_CLS + t, fb), sum);
        if (fb) ((bf16*)outv)[g * N_CLS + t] = __float2bfloat16(sum);
        else    ((float*)outv)[g * N_CLS + t] = sum;
    }
}

extern "C" void kernel_launch(void* const* d_in, const int* in_sizes, int n_in,
                              void* d_out, int out_size, void* d_ws, size_t ws_size,
                              hipStream_t stream) {
    (void)n_in; (void)ws_size; (void)in_sizes; (void)out_size;
    const void* x     = d_in[0];
    const int*  ei    = (const int*)d_in[1];
    const int*  batch = (const int*)d_in[2];
    const void* W1    = d_in[3];
    const void* b1    = d_in[4];
    const void* W2    = d_in[5];
    const void* b2    = d_in[6];
    const void* Wl    = d_in[7];
    const void* bl    = d_in[8];

    const int N = N_NODES, E = N_EDGES, F = IN_F, H = HID, G = N_GRAPH;

    char* ws = (char*)d_ws;
    size_t off = 0;
    auto alloc = [&](size_t bytes) -> void* {
        void* p = ws + off;
        off += (bytes + 511) & ~(size_t)511;
        return p;
    };
    unsigned char*  xs8  = (unsigned char*)alloc((size_t)N * F);       // fp8 prescaled x (6.4 MB)
    unsigned short* aggX = (unsigned short*)alloc((size_t)N * F * 2);  // bf16 A-partial @ x (12.8 MB)
    unsigned char*  XW2s8 = (unsigned char*)alloc((size_t)N * H);      // fp8 XW2 (12.8 MB) — must NOT alias aggX (k_gcn2l reads aggX while writing this)
    unsigned short* H2   = (unsigned short*)alloc((size_t)N * H * 2);  // bf16 (25.6 MB)
    unsigned short* w1t  = (unsigned short*)alloc((size_t)H * F * 2);
    unsigned short* w2t  = (unsigned short*)alloc((size_t)H * H * 2);
    int*   bucketCnt = (int*)alloc((size_t)NB * 16 * 4);   // zero region (padded: 1 line/bucket)
    int*   bucketBase = (int*)alloc((size_t)(NB + 1) * 4);
    int*   blockBase = (int*)alloc((size_t)PBLOCKS * NB * 4);
    unsigned* part  = (unsigned*)alloc((size_t)E * 4);     // packed (d&511)<<16 | s
    int*   gstart  = (int*)alloc((size_t)(G + 1) * 4);
    float* dinv    = (float*)alloc((size_t)N * 4);
    int*   rowptr  = (int*)alloc((size_t)(N + 1) * 4);
    int*   flags   = (int*)alloc(512);
    int*   col     = (int*)alloc((size_t)E * 4);
    size_t zero_bytes = (size_t)NB * 16 * 4;

    hipMemsetAsync(bucketCnt, 0, zero_bytes, stream);

    k_detect<<<1, 256, 0, stream>>>(ei, (const unsigned short*)x, flags);
    k_partA1<<<PBLOCKS, 256, 0, stream>>>(ei, bucketCnt, blockBase, flags, E, N);
    k_bscan<<<1, 128, 0, stream>>>(bucketCnt, bucketBase);
    k_partA2<<<PBLOCKS, 256, 0, stream>>>(ei, bucketBase, blockBase, part, flags, E, N);
    k_partB<<<NB, 256, 0, stream>>>(part, bucketBase, rowptr, dinv, col, N);

    // merged conversions (fp8 prescaled x + transposed weights + graph bounds)
    k_cvt<<<CVTX_BLOCKS + CVT1_BLOCKS + CVT2_BLOCKS + GB_BLOCKS, 256, 0, stream>>>(
        x, dinv, xs8, W1, w1t, W2, w2t, batch, gstart, flags);

    int g64 = (N + 63) >> 6;                   // 782 64-row blocks
    int aggBlocks = ((g64 + 7) >> 3) * 8 * 16; // 12544: XCD-aligned agg2 map
    int nbAgg = (N + 3) / 4;

    // layer 1 aggregate, then fused 2-layer GEMM (H1 lives in LDS), then layer-2 aggregate
    k_agg2<<<aggBlocks, 256, 0, stream>>>(xs8, rowptr, col, aggX, N);
    k_gcn2l<<<g64, 256, 0, stream>>>(aggX, w1t, w2t, XW2s8, N, dinv, b1, flags);
    k_agg4<<<nbAgg, 256, 0, stream>>>(XW2s8, rowptr, col, dinv, b2, flags, H2, N);
    // pool + classify (merged)
    k_poolfinal<<<G, 512, 0, stream>>>(H2, gstart, Wl, bl, flags, d_out);
}

// Round 13
// 251.690 us; speedup vs baseline: 1.1836x; 1.0141x over previous
//
#include <hip/hip_runtime.h>
#include <hip/hip_bf16.h>

typedef __hip_bfloat16 bf16;
typedef __attribute__((ext_vector_type(8))) short short8;
typedef __attribute__((ext_vector_type(4))) float f32x4;
typedef __attribute__((ext_vector_type(2))) float f32x2;

// ---- problem constants (fixed by reference file) ----
#define N_NODES 50000
#define N_EDGES 800000
#define IN_F    128
#define HID     256
#define N_CLS   10
#define N_GRAPH 256

// radix-partition CSR build
#define NB 98          // buckets = ceil(N / 512), bucket = d >> 9
#define PBLOCKS 256    // partition grid (A1/A2 edge blocks must match exactly)

// flags[0] = ints are int64 (read low words), flags[1] = floats are bf16
__device__ __forceinline__ int IG(const int* __restrict__ p, int i, int w) {
    return w ? p[2 * i] : p[i];
}
__device__ __forceinline__ float LF(const void* __restrict__ p, int i, int isbf) {
    return isbf ? __bfloat162float(((const bf16*)p)[i]) : ((const float*)p)[i];
}
__device__ __forceinline__ float b2f(unsigned short h) {
    union { unsigned u; float f; } c; c.u = ((unsigned)h) << 16; return c.f;
}
__device__ __forceinline__ unsigned short f2b(float x) {
    bf16 h = __float2bfloat16(x);
    union { bf16 b; unsigned short u; } c; c.b = h; return c.u;
}
// fp8 e4m3 byte -> float scaled by 2^-120 (fallback decode path)
__device__ __forceinline__ float f8s(unsigned b) {
    union { unsigned u; float f; } c;
    c.u = ((b & 0x80u) << 24) | ((b & 0x7Fu) << 20);
    return c.f;
}
#define F8SCALE 0x1p120f
// float -> OCP fp8 e4m3 (RTNE via bf16 intermediate; FTZ below subnormal range)
__device__ __forceinline__ unsigned f2fp8(float x) {
    unsigned short h = f2b(x * 0x1p-120f);
    unsigned s = ((unsigned)h >> 8) & 0x80u;
    unsigned mag = (unsigned)h & 0x7FFFu;
    unsigned r = (mag + 7u + ((mag >> 4) & 1u)) >> 4;
    if (r > 0x7Eu) r = 0x7Eu;
    return s | r;
}

#if defined(__has_builtin)
#if __has_builtin(__builtin_amdgcn_cvt_pk_f32_fp8)
#define HW_FP8 1
#endif
#if __has_builtin(__builtin_amdgcn_cvt_pk_fp8_f32)
#define HW_FP8E 1
#endif
#endif

// decode 2 fp8 bytes (low or high half of a dword) -> float2, true magnitudes
__device__ __forceinline__ f32x2 cvt2lo(unsigned v) {
#ifdef HW_FP8
    return __builtin_amdgcn_cvt_pk_f32_fp8((int)v, false);
#else
    f32x2 r; r[0] = f8s(v & 0xFF) * F8SCALE; r[1] = f8s((v >> 8) & 0xFF) * F8SCALE; return r;
#endif
}
__device__ __forceinline__ f32x2 cvt2hi(unsigned v) {
#ifdef HW_FP8
    return __builtin_amdgcn_cvt_pk_f32_fp8((int)v, true);
#else
    f32x2 r; r[0] = f8s((v >> 16) & 0xFF) * F8SCALE; r[1] = f8s(v >> 24) * F8SCALE; return r;
#endif
}
// pack 4 floats -> 4 fp8 bytes (HW packed cvt when available)
__device__ __forceinline__ unsigned pk4_fp8(float v0, float v1, float v2, float v3) {
#ifdef HW_FP8E
    int o = __builtin_amdgcn_cvt_pk_fp8_f32(v0, v1, 0, false);
    o = __builtin_amdgcn_cvt_pk_fp8_f32(v2, v3, o, true);
    return (unsigned)o;
#else
    return f2fp8(v0) | (f2fp8(v1) << 8) | (f2fp8(v2) << 16) | (f2fp8(v3) << 24);
#endif
}

// ---- partition pass A1 + flags writer ----
// blocks 0..255: LDS bucket histogram with LOCAL int64-detect (flags not yet
// written); iteration/guards identical to k_partA2. block 256: writes flags
// for all downstream kernels (k_detect launch deleted).
__global__ __launch_bounds__(256) void k_partA1(const int* __restrict__ ei, int* __restrict__ bucketCnt,
                                                int* __restrict__ blockBase,
                                                const unsigned short* __restrict__ x,
                                                int* __restrict__ flags, int E, int N) {
    int t = threadIdx.x;
    if (blockIdx.x == PBLOCKS) {
        __shared__ int nz, cnt;
        if (t == 0) { nz = 0; cnt = 0; }
        __syncthreads();
        int found = 0, c = 0;
        for (int s = 0; s < 4; ++s) {
            int idx = 2 * (t * 4 + s) + 1;
            if (ei[idx] != 0) found = 1;
        }
        for (int s = 0; s < 8; ++s) {
            unsigned short h = x[t * 8 + s];
            int e = (h >> 7) & 0xFF;
            if (e >= 110 && e <= 135) c++;
        }
        if (found) atomicAdd(&nz, 1);
        atomicAdd(&cnt, c);
        __syncthreads();
        if (t == 0) {
            flags[0] = (nz == 0) ? 1 : 0;
            flags[1] = (cnt > 1536) ? 1 : 0;
        }
        return;
    }
    __shared__ int h[NB];
    __shared__ int wsh;
    if (t == 0) wsh = 0;
    if (t < NB) h[t] = 0;
    __syncthreads();
    int found = 0;
    for (int s = 0; s < 4; ++s) {
        int idx = 2 * (t * 4 + s) + 1;
        if (ei[idx] != 0) found = 1;
    }
    if (found) atomicAdd(&wsh, 1);
    __syncthreads();
    int w = (wsh == 0) ? 1 : 0;
    for (int e = blockIdx.x * 256 + t; e < E; e += PBLOCKS * 256) {
        int d = IG(ei, E + e, w);
        int s = IG(ei, e, w);
        if ((unsigned)d < (unsigned)N && (unsigned)s < (unsigned)N)
            atomicAdd(&h[d >> 9], 1);
    }
    __syncthreads();
    if (t < NB)
        blockBase[blockIdx.x * NB + t] = atomicAdd(&bucketCnt[t * 16], h[t]);
}

// ---- 1-block exclusive scan of bucket counts ----
__global__ __launch_bounds__(128) void k_bscan(const int* __restrict__ bucketCnt,
                                               int* __restrict__ bucketBase) {
    __shared__ int s[128];
    int t = threadIdx.x;
    int v = (t < NB) ? bucketCnt[t * 16] : 0;
    s[t] = v;
    __syncthreads();
    for (int off = 1; off < 128; off <<= 1) {
        int add = (t >= off) ? s[t - off] : 0;
        __syncthreads();
        s[t] += add;
        __syncthreads();
    }
    if (t <= NB) bucketBase[t] = (t < NB) ? (s[t] - v) : s[NB - 1] + 0;
    if (t == NB - 1) bucketBase[NB] = s[t];  // total kept edges
}

// ---- partition pass A2: scatter packed edges into bucket-partitioned array ----
// MUST iterate identically to A1's edge blocks (same 256-block layout, same guards).
__global__ __launch_bounds__(256) void k_partA2(const int* __restrict__ ei,
                                                const int* __restrict__ bucketBase,
                                                const int* __restrict__ blockBase,
                                                unsigned* __restrict__ part,
                                                const int* __restrict__ flags, int E, int N) {
    __shared__ int cur[NB];
    int t = threadIdx.x;
    if (t < NB) cur[t] = bucketBase[t] + blockBase[blockIdx.x * NB + t];
    __syncthreads();
    int w = flags[0];
    for (int e = blockIdx.x * 256 + t; e < E; e += PBLOCKS * 256) {
        int d = IG(ei, E + e, w);
        int s = IG(ei, e, w);
        if ((unsigned)d < (unsigned)N && (unsigned)s < (unsigned)N) {
            int slot = atomicAdd(&cur[d >> 9], 1);
            part[slot] = ((unsigned)(d & 511) << 16) | (unsigned)s;
        }
    }
}

// ---- partition pass B (+ merged weight transposes + gstart) ----
// blocks 0..97: per-bucket rowptr/dinv/col. blocks 98..225: w1t transpose.
// 226..481: w2t transpose. 482..677: graph-start bounds. flags are ready
// (written by A1). The merged work fills the GPU during the 98-block pass.
#define PB_W1 98
#define PB_W2 226
#define PB_GB 482
#define PB_TOT 678
__global__ __launch_bounds__(256) void k_partB(const unsigned* __restrict__ part,
                                               const int* __restrict__ bucketBase,
                                               int* __restrict__ rowptr, float* __restrict__ dinv,
                                               int* __restrict__ col,
                                               const void* __restrict__ W1, unsigned short* __restrict__ w1t,
                                               const void* __restrict__ W2, unsigned short* __restrict__ w2t,
                                               const int* __restrict__ batch, int* __restrict__ gstart,
                                               const int* __restrict__ flags, int N) {
    int b = blockIdx.x, t = threadIdx.x;
    if (b >= NB) {
        int fb = flags[1];
        if (b < PB_W2) {
            int i = (b - PB_W1) * 256 + t;
            int n = i >> 7, k = i & 127;
            w1t[i] = f2b(LF(W1, k * 256 + n, fb));
        } else if (b < PB_GB) {
            int i = (b - PB_W2) * 256 + t;
            int n = i >> 8, k = i & 255;
            w2t[i] = f2b(LF(W2, k * 256 + n, fb));
        } else {
            int i = (b - PB_GB) * 256 + t;
            if (i <= N_NODES) {
                int w = flags[0];
                int prev = (i == 0) ? -1 : IG(batch, i - 1, w);
                int cur  = (i == N_NODES) ? N_GRAPH : IG(batch, i, w);
                if (prev < -1) prev = -1;
                if (cur > N_GRAPH) cur = N_GRAPH;
                for (int g = prev + 1; g <= cur; ++g)
                    if (g >= 0 && g <= N_GRAPH) gstart[g] = i;
            }
        }
        return;
    }
    __shared__ int hist[512];
    __shared__ int scn[512];
    __shared__ int pair[256];
    int s0 = bucketBase[b], e0 = bucketBase[b + 1];
    hist[t] = 0; hist[t + 256] = 0;
    __syncthreads();
    for (int j = s0 + t; j < e0; j += 256)
        atomicAdd(&hist[part[j] >> 16], 1);
    __syncthreads();
    // exclusive scan over 512 via pair-sums
    int a0 = hist[2 * t], a1 = hist[2 * t + 1];
    int pv = a0 + a1;
    pair[t] = pv;
    __syncthreads();
    for (int off = 1; off < 256; off <<= 1) {
        int add = (t >= off) ? pair[t - off] : 0;
        __syncthreads();
        pair[t] += add;
        __syncthreads();
    }
    int pbase = pair[t] - pv;  // exclusive pair base
    scn[2 * t] = pbase;
    scn[2 * t + 1] = pbase + a0;
    __syncthreads();
#pragma unroll
    for (int hh = 0; hh < 2; ++hh) {
        int l = t + hh * 256;
        int node = b * 512 + l;
        if (node < N) {
            rowptr[node] = s0 + scn[l];
            dinv[node] = rsqrtf((float)(hist[l] + 1));  // +1 self loop
        }
    }
    if (b == 0 && t == 0) rowptr[N] = bucketBase[NB];
    // reuse scn as cursors (already = local base)
    __syncthreads();
    for (int j = s0 + t; j < e0; j += 256) {
        unsigned p = part[j];
        int pos = s0 + atomicAdd(&scn[p >> 16], 1);
        col[pos] = (int)(p & 0xFFFFu);
    }
}

// ---- xs8 = fp8(x*dinv) (CVTX only; transposes/gstart moved into k_partB) ----
#define CVTX_BLOCKS 6250   // N*IN_F/4 / 256
__global__ __launch_bounds__(256) void k_cvt(const void* __restrict__ x, const float* __restrict__ dinv,
                                             unsigned char* __restrict__ xs8,
                                             const int* __restrict__ flags) {
    int fb = flags[1];
    int gid = blockIdx.x * 256 + threadIdx.x;
    int row = gid >> 5;  // 32 4-elem chunks per 128-feat row
    float d = dinv[row];
    float vx, vy, vz, vw;
    if (fb) {
        ushort4 v = ((const ushort4*)x)[gid];
        vx = b2f(v.x); vy = b2f(v.y); vz = b2f(v.z); vw = b2f(v.w);
    } else {
        float4 v = ((const float4*)x)[gid];
        vx = v.x; vy = v.y; vz = v.z; vw = v.w;
    }
    ((unsigned*)xs8)[gid] = pk4_fp8(vx * d, vy * d, vz * d, vw * d);
}

// ---- fused 2-layer GCN GEMM: per 64-row block, both layers, H1 never leaves LDS ----
// (r9-validated) stage0: stage aggX[64x128] -> LDS. phase1 (K=128): H1 tile =
// relu((A@W1)*dinv + b1) -> LDS bf16 [64][264]. phase2 (K=256): A from the LDS
// H1 tile, B2 (128KB, L2-resident) from global; fp8 out via LDS-transpose
// epilogue. r11 lesson: do NOT pull the CSR gather in here.
__global__ __launch_bounds__(256) void k_gcn2l(const unsigned short* __restrict__ A,
                                               const unsigned short* __restrict__ B1t,
                                               const unsigned short* __restrict__ B2t,
                                               unsigned char* __restrict__ C8, int M,
                                               const float* __restrict__ dinv,
                                               const void* __restrict__ bias1,
                                               const int* __restrict__ flags) {
    __shared__ unsigned short As1[64 * 136];  // 17.4 KB aggX tile (128 cols); reused as fp8 C-stage
    __shared__ unsigned short Hs[64 * 264];   // 33.8 KB H1 tile (256 cols, 528B stride -> 2-way banks)
    int t = threadIdx.x;
    int lane = t & 63;
    int w = t >> 6;               // wave -> 64-col slice
    int bm = blockIdx.x * 64;
    int l15 = lane & 15, quad = lane >> 4;
    int fb = flags[1];

    // ---- stage aggX tile (rows >= M read adjacent workspace; discarded later)
    {
        const uint4* src = (const uint4*)&A[(size_t)bm * 128];
#pragma unroll
        for (int j = 0; j < 4; ++j) {
            int f = t + j * 256;           // uint4 index 0..1023 (16 per row)
            int row = f >> 4, cu = f & 15;
            *(uint4*)&As1[row * 136 + cu * 8] = src[(size_t)row * 16 + cu];
        }
    }
    __syncthreads();

    f32x4 acc[4][4];
#pragma unroll
    for (int ar = 0; ar < 4; ++ar)
#pragma unroll
        for (int tt = 0; tt < 4; ++tt) acc[ar][tt] = (f32x4){0.f, 0.f, 0.f, 0.f};

    // ---- phase 1: K=128 (A from LDS, B1 from L2)
#pragma unroll
    for (int ks = 0; ks < 4; ++ks) {
        short8 a[4], b[4];
#pragma unroll
        for (int ar = 0; ar < 4; ++ar)
            a[ar] = *(const short8*)&As1[(ar * 16 + l15) * 136 + ks * 32 + quad * 8];
#pragma unroll
        for (int tt = 0; tt < 4; ++tt)
            b[tt] = *(const short8*)&B1t[(size_t)(w * 64 + tt * 16 + l15) * 128 + ks * 32 + quad * 8];
#pragma unroll
        for (int tt = 0; tt < 4; ++tt)
#pragma unroll
            for (int ar = 0; ar < 4; ++ar)
                acc[ar][tt] = __builtin_amdgcn_mfma_f32_16x16x32_bf16(b[tt], a[ar], acc[ar][tt], 0, 0, 0);
    }

    float drow[4];
#pragma unroll
    for (int ar = 0; ar < 4; ++ar) {
        int row = bm + ar * 16 + l15;
        drow[ar] = (row < M) ? dinv[row] : 1.f;
    }
    // phase-1 epilogue: H1 = relu(acc*dinv + b1) -> bf16 LDS tile
#pragma unroll
    for (int tt = 0; tt < 4; ++tt) {
        int colb = w * 64 + tt * 16 + quad * 4;
        float bc[4];
#pragma unroll
        for (int rr = 0; rr < 4; ++rr) bc[rr] = LF(bias1, colb + rr, fb);
#pragma unroll
        for (int ar = 0; ar < 4; ++ar) {
            ushort4 o;
            o.x = f2b(fmaxf(fmaf(acc[ar][tt][0], drow[ar], bc[0]), 0.f));
            o.y = f2b(fmaxf(fmaf(acc[ar][tt][1], drow[ar], bc[1]), 0.f));
            o.z = f2b(fmaxf(fmaf(acc[ar][tt][2], drow[ar], bc[2]), 0.f));
            o.w = f2b(fmaxf(fmaf(acc[ar][tt][3], drow[ar], bc[3]), 0.f));
            *(ushort4*)&Hs[(ar * 16 + l15) * 264 + colb] = o;
            acc[ar][tt] = (f32x4){0.f, 0.f, 0.f, 0.f};   // re-init for phase 2
        }
    }
    __syncthreads();   // H1 tile complete (all waves' column slices)

    // ---- phase 2: K=256 (A from LDS H1 tile, B2 from L2)
#pragma unroll
    for (int ks = 0; ks < 8; ++ks) {
        short8 a[4], b[4];
#pragma unroll
        for (int ar = 0; ar < 4; ++ar)
            a[ar] = *(const short8*)&Hs[(ar * 16 + l15) * 264 + ks * 32 + quad * 8];
#pragma unroll
        for (int tt = 0; tt < 4; ++tt)
            b[tt] = *(const short8*)&B2t[(size_t)(w * 64 + tt * 16 + l15) * 256 + ks * 32 + quad * 8];
#pragma unroll
        for (int tt = 0; tt < 4; ++tt)
#pragma unroll
            for (int ar = 0; ar < 4; ++ar)
                acc[ar][tt] = __builtin_amdgcn_mfma_f32_16x16x32_bf16(b[tt], a[ar], acc[ar][tt], 0, 0, 0);
    }

    // phase-2 epilogue: fp8(acc*dinv) via LDS transpose (As1 region dead since phase 1)
    unsigned* Cs = (unsigned*)As1;   // row stride 68 dwords (272 B, 16B-aligned)
    __syncthreads();                 // all phase-1 LDS reads done before overwrite
#pragma unroll
    for (int tt = 0; tt < 4; ++tt) {
#pragma unroll
        for (int ar = 0; ar < 4; ++ar) {
            float v0 = acc[ar][tt][0] * drow[ar];
            float v1 = acc[ar][tt][1] * drow[ar];
            float v2 = acc[ar][tt][2] * drow[ar];
            float v3 = acc[ar][tt][3] * drow[ar];
            Cs[(ar * 16 + l15) * 68 + w * 16 + tt * 4 + quad] = pk4_fp8(v0, v1, v2, v3);
        }
    }
    __syncthreads();
    int r = t >> 2, h = t & 3;       // 64 rows x 4 chunks of 64 B
    if (bm + r < M) {
        const unsigned* src = Cs + r * 68 + h * 16;
        uint4* dst = (uint4*)&C8[(size_t)(bm + r) * 256 + h * 64];
#pragma unroll
        for (int j = 0; j < 4; ++j) dst[j] = *(const uint4*)(src + j * 4);
    }
}

// ---- agg over 128-feat fp8 rows, XCD-aligned block map (64-row groups) ----
__global__ __launch_bounds__(256) void k_agg2(const unsigned char* __restrict__ XS,
                                              const int* __restrict__ rowptr, const int* __restrict__ col,
                                              unsigned short* __restrict__ Hout, int N) {
    int jb = blockIdx.x;
    int x8 = jb & 7, k = jb >> 3;
    int gIdx = k >> 4, win = k & 15;
    int node0 = (gIdx * 8 + x8) * 64 + win * 4;
    int lane = threadIdx.x & 63;
    int i = node0 + (threadIdx.x >> 6);
    if (i >= N) return;
    int fo = lane * 2;
    unsigned sv = *(const unsigned short*)&XS[(size_t)i * 128 + fo];
    f32x2 a = cvt2lo(sv);
    int s = rowptr[i], e = rowptr[i + 1];
    int j = s;
    while (j + 16 <= e) {
        unsigned v[16];
#pragma unroll
        for (int q = 0; q < 16; ++q)
            v[q] = *(const unsigned short*)&XS[(size_t)col[j + q] * 128 + fo];
#pragma unroll
        for (int q = 0; q < 16; ++q) a += cvt2lo(v[q]);
        j += 16;
    }
    if (j + 8 <= e) {
        unsigned v[8];
#pragma unroll
        for (int q = 0; q < 8; ++q)
            v[q] = *(const unsigned short*)&XS[(size_t)col[j + q] * 128 + fo];
#pragma unroll
        for (int q = 0; q < 8; ++q) a += cvt2lo(v[q]);
        j += 8;
    }
    if (j + 4 <= e) {
        unsigned v[4];
#pragma unroll
        for (int q = 0; q < 4; ++q)
            v[q] = *(const unsigned short*)&XS[(size_t)col[j + q] * 128 + fo];
#pragma unroll
        for (int q = 0; q < 4; ++q) a += cvt2lo(v[q]);
        j += 4;
    }
    for (; j < e; ++j)
        a += cvt2lo(*(const unsigned short*)&XS[(size_t)col[j] * 128 + fo]);
    ushort2 o;
    o.x = f2b(a[0]); o.y = f2b(a[1]);
    *(ushort2*)&Hout[(size_t)i * 128 + fo] = o;
}

// ---- agg over 256-feat fp8 rows -> per-block f32 POOL PARTIALS (H2 deleted) ----
// batch sorted => a 4-node block is uniform (all one graph) iff it is fully
// inside that graph; uniform blocks write one f32x256 partial row (no atomics),
// boundary blocks (~255) atomicAdd per node into pooledX[g]. b2 is folded
// analytically into k_poolfinal. Traffic: 12.8 MB write vs 25.6 MB H2.
__global__ __launch_bounds__(256) void k_agg4p(const unsigned char* __restrict__ XW,
                                               const int* __restrict__ rowptr, const int* __restrict__ col,
                                               const float* __restrict__ dinv,
                                               const int* __restrict__ batch,
                                               const int* __restrict__ flags,
                                               float* __restrict__ partial,
                                               float* __restrict__ pooledX, int N) {
    __shared__ float red[4][256];
    __shared__ int gs[4];
    int t = threadIdx.x;
    int lane = t & 63, sub = t >> 6;
    int i = blockIdx.x * 4 + sub;
    int fo = lane * 4;
    float v[4] = {0.f, 0.f, 0.f, 0.f};
    int g = -1;
    if (i < N) {
        g = IG(batch, i, flags[0]);
        unsigned sv = *(const unsigned*)&XW[(size_t)i * 256 + fo];
        f32x2 a01 = cvt2lo(sv), a23 = cvt2hi(sv);
        int s = rowptr[i], e = rowptr[i + 1];
        int j = s;
        while (j + 16 <= e) {
            unsigned vv[16];
#pragma unroll
            for (int q = 0; q < 16; ++q)
                vv[q] = *(const unsigned*)&XW[(size_t)col[j + q] * 256 + fo];
#pragma unroll
            for (int q = 0; q < 16; ++q) { a01 += cvt2lo(vv[q]); a23 += cvt2hi(vv[q]); }
            j += 16;
        }
        if (j + 8 <= e) {
            unsigned vv[8];
#pragma unroll
            for (int q = 0; q < 8; ++q)
                vv[q] = *(const unsigned*)&XW[(size_t)col[j + q] * 256 + fo];
#pragma unroll
            for (int q = 0; q < 8; ++q) { a01 += cvt2lo(vv[q]); a23 += cvt2hi(vv[q]); }
            j += 8;
        }
        if (j + 4 <= e) {
            unsigned vv[4];
#pragma unroll
            for (int q = 0; q < 4; ++q)
                vv[q] = *(const unsigned*)&XW[(size_t)col[j + q] * 256 + fo];
#pragma unroll
            for (int q = 0; q < 4; ++q) { a01 += cvt2lo(vv[q]); a23 += cvt2hi(vv[q]); }
            j += 4;
        }
        for (; j < e; ++j) {
            unsigned vv = *(const unsigned*)&XW[(size_t)col[j] * 256 + fo];
            a01 += cvt2lo(vv); a23 += cvt2hi(vv);
        }
        float di = dinv[i];
        v[0] = a01[0] * di; v[1] = a01[1] * di;
        v[2] = a23[0] * di; v[3] = a23[1] * di;
    }
    if (lane == 0) gs[sub] = g;
#pragma unroll
    for (int k2 = 0; k2 < 4; ++k2) red[sub][fo + k2] = v[k2];
    __syncthreads();
    bool uni = (gs[0] >= 0) && gs[0] == gs[1] && gs[1] == gs[2] && gs[2] == gs[3];
    if (uni) {
        float s4 = red[0][t] + red[1][t] + red[2][t] + red[3][t];
        partial[(size_t)blockIdx.x * 256 + t] = s4;
    } else if (g >= 0) {
#pragma unroll
        for (int k2 = 0; k2 < 4; ++k2)
            atomicAdd(&pooledX[g * 256 + fo + k2], v[k2]);
    }
}

// ---- classifier from pool partials: one block (512 thr) per graph ----
// graph g sums partial rows of its fully-inside blocks [ceil(s/4), floor(e/4))
// plus the boundary atomics in pooledX[g]; p = sum/cnt + b2; out = p@Wlin+blin.
__global__ __launch_bounds__(512) void k_poolfinal(const float* __restrict__ partial,
                                                   const float* __restrict__ pooledX,
                                                   const int* __restrict__ gstart,
                                                   const void* __restrict__ b2,
                                                   const void* __restrict__ Wlin,
                                                   const void* __restrict__ blin,
                                                   const int* __restrict__ flags,
                                                   void* __restrict__ outv) {
    __shared__ float red[8][256];
    __shared__ float p[256];
    int g = blockIdx.x, t = threadIdx.x;
    int sub = t >> 6, lane = t & 63;
    int s = gstart[g], e = gstart[g + 1];
    int cnt = e - s;
    int b0 = (s + 3) >> 2, b1 = e >> 2;   // fully-inside partial blocks [b0, b1)
    int fo = lane * 4;
    float a0 = 0.f, a1 = 0.f, a2 = 0.f, a3 = 0.f;
    for (int b = b0 + sub; b < b1; b += 8) {
        float4 v = *(const float4*)&partial[(size_t)b * 256 + fo];
        a0 += v.x; a1 += v.y; a2 += v.z; a3 += v.w;
    }
    red[sub][fo + 0] = a0;
    red[sub][fo + 1] = a1;
    red[sub][fo + 2] = a2;
    red[sub][fo + 3] = a3;
    __syncthreads();
    int fb = flags[1];
    if (t < 256) {
        float sum8 = pooledX[g * 256 + t];
#pragma unroll
        for (int q = 0; q < 8; ++q) sum8 += red[q][t];
        float inv = 1.f / fmaxf((float)cnt, 1.f);
        float bb = (cnt > 0) ? LF(b2, t, fb) : 0.f;
        p[t] = sum8 * inv + bb;
    }
    __syncthreads();
    if (t < N_CLS) {
        float sum = LF(blin, t, fb);
        for (int f = 0; f < HID; ++f) sum = fmaf(p[f], LF(Wlin, f * N_CLS + t, fb), sum);
        if (fb) ((bf16*)outv)[g * N_CLS + t] = __float2bfloat16(sum);
        else    ((float*)outv)[g * N_CLS + t] = sum;
    }
}

extern "C" void kernel_launch(void* const* d_in, const int* in_sizes, int n_in,
                              void* d_out, int out_size, void* d_ws, size_t ws_size,
                              hipStream_t stream) {
    (void)n_in; (void)ws_size; (void)in_sizes; (void)out_size;
    const void* x     = d_in[0];
    const int*  ei    = (const int*)d_in[1];
    const int*  batch = (const int*)d_in[2];
    const void* W1    = d_in[3];
    const void* b1    = d_in[4];
    const void* W2    = d_in[5];
    const void* b2    = d_in[6];
    const void* Wl    = d_in[7];
    const void* bl    = d_in[8];

    const int N = N_NODES, E = N_EDGES, F = IN_F, H = HID, G = N_GRAPH;

    char* ws = (char*)d_ws;
    size_t off = 0;
    auto alloc = [&](size_t bytes) -> void* {
        void* p = ws + off;
        off += (bytes + 511) & ~(size_t)511;
        return p;
    };
    unsigned char*  xs8  = (unsigned char*)alloc((size_t)N * F);       // fp8 prescaled x (6.4 MB)
    unsigned short* aggX = (unsigned short*)alloc((size_t)N * F * 2);  // bf16 A-partial @ x (12.8 MB)
    unsigned char*  XW2s8 = (unsigned char*)alloc((size_t)N * H);      // fp8 XW2 (12.8 MB) — must NOT alias aggX (k_gcn2l reads aggX while writing this)
    float*          partial = (float*)alloc((size_t)(N / 4) * H * 4);  // f32 pool partials (12.8 MB)
    float*          pooledX = (float*)alloc((size_t)G * H * 4);        // boundary atomics (256 KB, zeroed)
    unsigned short* w1t  = (unsigned short*)alloc((size_t)H * F * 2);
    unsigned short* w2t  = (unsigned short*)alloc((size_t)H * H * 2);
    int*   bucketCnt = (int*)alloc((size_t)NB * 16 * 4);   // zero region (padded: 1 line/bucket)
    int*   bucketBase = (int*)alloc((size_t)(NB + 1) * 4);
    int*   blockBase = (int*)alloc((size_t)PBLOCKS * NB * 4);
    unsigned* part  = (unsigned*)alloc((size_t)E * 4);     // packed (d&511)<<16 | s
    int*   gstart  = (int*)alloc((size_t)(G + 1) * 4);
    float* dinv    = (float*)alloc((size_t)N * 4);
    int*   rowptr  = (int*)alloc((size_t)(N + 1) * 4);
    int*   flags   = (int*)alloc(512);
    int*   col     = (int*)alloc((size_t)E * 4);
    size_t zero_bytes = (size_t)NB * 16 * 4;

    hipMemsetAsync(bucketCnt, 0, zero_bytes, stream);
    hipMemsetAsync(pooledX, 0, (size_t)G * H * 4, stream);

    // A1 (edge histogram with local detect) + flags writer (block 256)
    k_partA1<<<PBLOCKS + 1, 256, 0, stream>>>(ei, bucketCnt, blockBase,
                                              (const unsigned short*)x, flags, E, N);
    k_bscan<<<1, 128, 0, stream>>>(bucketCnt, bucketBase);
    k_partA2<<<PBLOCKS, 256, 0, stream>>>(ei, bucketBase, blockBase, part, flags, E, N);
    // partB buckets + merged weight transposes + gstart
    k_partB<<<PB_TOT, 256, 0, stream>>>(part, bucketBase, rowptr, dinv, col,
                                        W1, w1t, W2, w2t, batch, gstart, flags, N);
    // xs8 = fp8(x * dinv)
    k_cvt<<<CVTX_BLOCKS, 256, 0, stream>>>(x, dinv, xs8, flags);

    int g64 = (N + 63) >> 6;                   // 782 64-row blocks
    int aggBlocks = ((g64 + 7) >> 3) * 8 * 16; // 12544: XCD-aligned agg2 map
    int nbAgg = (N + 3) / 4;                   // 12500 (N divisible by 4)

    // layer 1 aggregate, fused 2-layer GEMM (H1 in LDS), layer-2 aggregate -> pool partials
    k_agg2<<<aggBlocks, 256, 0, stream>>>(xs8, rowptr, col, aggX, N);
    k_gcn2l<<<g64, 256, 0, stream>>>(aggX, w1t, w2t, XW2s8, N, dinv, b1, flags);
    k_agg4p<<<nbAgg, 256, 0, stream>>>(XW2s8, rowptr, col, dinv, batch, flags, partial, pooledX, N);
    // classifier from partials
    k_poolfinal<<<G, 512, 0, stream>>>(partial, pooledX, gstart, b2, Wl, bl, flags, d_out);
}

// Round 14
// 242.553 us; speedup vs baseline: 1.2282x; 1.0377x over previous
//
#include <hip/hip_runtime.h>
#include <hip/hip_bf16.h>

typedef __hip_bfloat16 bf16;
typedef __attribute__((ext_vector_type(8))) short short8;
typedef __attribute__((ext_vector_type(4))) float f32x4;
typedef __attribute__((ext_vector_type(2))) float f32x2;

// ---- problem constants (fixed by reference file) ----
#define N_NODES 50000
#define N_EDGES 800000
#define IN_F    128
#define HID     256
#define N_CLS   10
#define N_GRAPH 256

// radix-partition CSR build
#define NB 98          // buckets = ceil(N / 512), bucket = d >> 9
#define PBLOCKS 256    // partition grid (A1/A2 edge blocks must match exactly)

// flags[0] = ints are int64 (read low words), flags[1] = floats are bf16
__device__ __forceinline__ int IG(const int* __restrict__ p, int i, int w) {
    return w ? p[2 * i] : p[i];
}
__device__ __forceinline__ float LF(const void* __restrict__ p, int i, int isbf) {
    return isbf ? __bfloat162float(((const bf16*)p)[i]) : ((const float*)p)[i];
}
__device__ __forceinline__ float b2f(unsigned short h) {
    union { unsigned u; float f; } c; c.u = ((unsigned)h) << 16; return c.f;
}
__device__ __forceinline__ unsigned short f2b(float x) {
    bf16 h = __float2bfloat16(x);
    union { bf16 b; unsigned short u; } c; c.b = h; return c.u;
}
// fp8 e4m3 byte -> float scaled by 2^-120 (fallback decode path)
__device__ __forceinline__ float f8s(unsigned b) {
    union { unsigned u; float f; } c;
    c.u = ((b & 0x80u) << 24) | ((b & 0x7Fu) << 20);
    return c.f;
}
#define F8SCALE 0x1p120f
// float -> OCP fp8 e4m3 (RTNE via bf16 intermediate; FTZ below subnormal range)
__device__ __forceinline__ unsigned f2fp8(float x) {
    unsigned short h = f2b(x * 0x1p-120f);
    unsigned s = ((unsigned)h >> 8) & 0x80u;
    unsigned mag = (unsigned)h & 0x7FFFu;
    unsigned r = (mag + 7u + ((mag >> 4) & 1u)) >> 4;
    if (r > 0x7Eu) r = 0x7Eu;
    return s | r;
}

#if defined(__has_builtin)
#if __has_builtin(__builtin_amdgcn_cvt_pk_f32_fp8)
#define HW_FP8 1
#endif
#if __has_builtin(__builtin_amdgcn_cvt_pk_fp8_f32)
#define HW_FP8E 1
#endif
#endif

// decode 2 fp8 bytes (low or high half of a dword) -> float2, true magnitudes
__device__ __forceinline__ f32x2 cvt2lo(unsigned v) {
#ifdef HW_FP8
    return __builtin_amdgcn_cvt_pk_f32_fp8((int)v, false);
#else
    f32x2 r; r[0] = f8s(v & 0xFF) * F8SCALE; r[1] = f8s((v >> 8) & 0xFF) * F8SCALE; return r;
#endif
}
__device__ __forceinline__ f32x2 cvt2hi(unsigned v) {
#ifdef HW_FP8
    return __builtin_amdgcn_cvt_pk_f32_fp8((int)v, true);
#else
    f32x2 r; r[0] = f8s((v >> 16) & 0xFF) * F8SCALE; r[1] = f8s(v >> 24) * F8SCALE; return r;
#endif
}
// pack 4 floats -> 4 fp8 bytes (HW packed cvt when available)
__device__ __forceinline__ unsigned pk4_fp8(float v0, float v1, float v2, float v3) {
#ifdef HW_FP8E
    int o = __builtin_amdgcn_cvt_pk_fp8_f32(v0, v1, 0, false);
    o = __builtin_amdgcn_cvt_pk_fp8_f32(v2, v3, o, true);
    return (unsigned)o;
#else
    return f2fp8(v0) | (f2fp8(v1) << 8) | (f2fp8(v2) << 16) | (f2fp8(v3) << 24);
#endif
}

// ---- partition pass A1 + flags writer ----
// blocks 0..255: LDS bucket histogram with LOCAL int64-detect; iteration and
// guards identical to k_partA2. block 256: writes flags for downstream kernels.
__global__ __launch_bounds__(256) void k_partA1(const int* __restrict__ ei, int* __restrict__ bucketCnt,
                                                int* __restrict__ blockBase,
                                                const unsigned short* __restrict__ x,
                                                int* __restrict__ flags, int E, int N) {
    int t = threadIdx.x;
    if (blockIdx.x == PBLOCKS) {
        __shared__ int nz, cnt;
        if (t == 0) { nz = 0; cnt = 0; }
        __syncthreads();
        int found = 0, c = 0;
        for (int s = 0; s < 4; ++s) {
            int idx = 2 * (t * 4 + s) + 1;
            if (ei[idx] != 0) found = 1;
        }
        for (int s = 0; s < 8; ++s) {
            unsigned short h = x[t * 8 + s];
            int e = (h >> 7) & 0xFF;
            if (e >= 110 && e <= 135) c++;
        }
        if (found) atomicAdd(&nz, 1);
        atomicAdd(&cnt, c);
        __syncthreads();
        if (t == 0) {
            flags[0] = (nz == 0) ? 1 : 0;
            flags[1] = (cnt > 1536) ? 1 : 0;
        }
        return;
    }
    __shared__ int h[NB];
    __shared__ int wsh;
    if (t == 0) wsh = 0;
    if (t < NB) h[t] = 0;
    __syncthreads();
    int found = 0;
    for (int s = 0; s < 4; ++s) {
        int idx = 2 * (t * 4 + s) + 1;
        if (ei[idx] != 0) found = 1;
    }
    if (found) atomicAdd(&wsh, 1);
    __syncthreads();
    int w = (wsh == 0) ? 1 : 0;
    for (int e = blockIdx.x * 256 + t; e < E; e += PBLOCKS * 256) {
        int d = IG(ei, E + e, w);
        int s = IG(ei, e, w);
        if ((unsigned)d < (unsigned)N && (unsigned)s < (unsigned)N)
            atomicAdd(&h[d >> 9], 1);
    }
    __syncthreads();
    if (t < NB)
        blockBase[blockIdx.x * NB + t] = atomicAdd(&bucketCnt[t * 16], h[t]);
}

// ---- 1-block exclusive scan of bucket counts ----
__global__ __launch_bounds__(128) void k_bscan(const int* __restrict__ bucketCnt,
                                               int* __restrict__ bucketBase) {
    __shared__ int s[128];
    int t = threadIdx.x;
    int v = (t < NB) ? bucketCnt[t * 16] : 0;
    s[t] = v;
    __syncthreads();
    for (int off = 1; off < 128; off <<= 1) {
        int add = (t >= off) ? s[t - off] : 0;
        __syncthreads();
        s[t] += add;
        __syncthreads();
    }
    if (t <= NB) bucketBase[t] = (t < NB) ? (s[t] - v) : s[NB - 1] + 0;
    if (t == NB - 1) bucketBase[NB] = s[t];  // total kept edges
}

// ---- partition pass A2: scatter packed edges into bucket-partitioned array ----
// MUST iterate identically to A1's edge blocks (same 256-block layout, same guards).
__global__ __launch_bounds__(256) void k_partA2(const int* __restrict__ ei,
                                                const int* __restrict__ bucketBase,
                                                const int* __restrict__ blockBase,
                                                unsigned* __restrict__ part,
                                                const int* __restrict__ flags, int E, int N) {
    __shared__ int cur[NB];
    int t = threadIdx.x;
    if (t < NB) cur[t] = bucketBase[t] + blockBase[blockIdx.x * NB + t];
    __syncthreads();
    int w = flags[0];
    for (int e = blockIdx.x * 256 + t; e < E; e += PBLOCKS * 256) {
        int d = IG(ei, E + e, w);
        int s = IG(ei, e, w);
        if ((unsigned)d < (unsigned)N && (unsigned)s < (unsigned)N) {
            int slot = atomicAdd(&cur[d >> 9], 1);
            part[slot] = ((unsigned)(d & 511) << 16) | (unsigned)s;
        }
    }
}

// ---- partition pass B (+ merged weight transposes + gstart) ----
// blocks 0..97: per-bucket rowptr/dinv/col. 98..225: w1t. 226..481: w2t.
// 482..677: graph-start bounds.
#define PB_W1 98
#define PB_W2 226
#define PB_GB 482
#define PB_TOT 678
__global__ __launch_bounds__(256) void k_partB(const unsigned* __restrict__ part,
                                               const int* __restrict__ bucketBase,
                                               int* __restrict__ rowptr, float* __restrict__ dinv,
                                               int* __restrict__ col,
                                               const void* __restrict__ W1, unsigned short* __restrict__ w1t,
                                               const void* __restrict__ W2, unsigned short* __restrict__ w2t,
                                               const int* __restrict__ batch, int* __restrict__ gstart,
                                               const int* __restrict__ flags, int N) {
    int b = blockIdx.x, t = threadIdx.x;
    if (b >= NB) {
        int fb = flags[1];
        if (b < PB_W2) {
            int i = (b - PB_W1) * 256 + t;
            int n = i >> 7, k = i & 127;
            w1t[i] = f2b(LF(W1, k * 256 + n, fb));
        } else if (b < PB_GB) {
            int i = (b - PB_W2) * 256 + t;
            int n = i >> 8, k = i & 255;
            w2t[i] = f2b(LF(W2, k * 256 + n, fb));
        } else {
            int i = (b - PB_GB) * 256 + t;
            if (i <= N_NODES) {
                int w = flags[0];
                int prev = (i == 0) ? -1 : IG(batch, i - 1, w);
                int cur  = (i == N_NODES) ? N_GRAPH : IG(batch, i, w);
                if (prev < -1) prev = -1;
                if (cur > N_GRAPH) cur = N_GRAPH;
                for (int g = prev + 1; g <= cur; ++g)
                    if (g >= 0 && g <= N_GRAPH) gstart[g] = i;
            }
        }
        return;
    }
    __shared__ int hist[512];
    __shared__ int scn[512];
    __shared__ int pair[256];
    int s0 = bucketBase[b], e0 = bucketBase[b + 1];
    hist[t] = 0; hist[t + 256] = 0;
    __syncthreads();
    for (int j = s0 + t; j < e0; j += 256)
        atomicAdd(&hist[part[j] >> 16], 1);
    __syncthreads();
    // exclusive scan over 512 via pair-sums
    int a0 = hist[2 * t], a1 = hist[2 * t + 1];
    int pv = a0 + a1;
    pair[t] = pv;
    __syncthreads();
    for (int off = 1; off < 256; off <<= 1) {
        int add = (t >= off) ? pair[t - off] : 0;
        __syncthreads();
        pair[t] += add;
        __syncthreads();
    }
    int pbase = pair[t] - pv;  // exclusive pair base
    scn[2 * t] = pbase;
    scn[2 * t + 1] = pbase + a0;
    __syncthreads();
#pragma unroll
    for (int hh = 0; hh < 2; ++hh) {
        int l = t + hh * 256;
        int node = b * 512 + l;
        if (node < N) {
            rowptr[node] = s0 + scn[l];
            dinv[node] = rsqrtf((float)(hist[l] + 1));  // +1 self loop
        }
    }
    if (b == 0 && t == 0) rowptr[N] = bucketBase[NB];
    // reuse scn as cursors (already = local base)
    __syncthreads();
    for (int j = s0 + t; j < e0; j += 256) {
        unsigned p = part[j];
        int pos = s0 + atomicAdd(&scn[p >> 16], 1);
        col[pos] = (int)(p & 0xFFFFu);
    }
}

// ---- xs8 = fp8(x*dinv) ----
#define CVTX_BLOCKS 6250   // N*IN_F/4 / 256
__global__ __launch_bounds__(256) void k_cvt(const void* __restrict__ x, const float* __restrict__ dinv,
                                             unsigned char* __restrict__ xs8,
                                             const int* __restrict__ flags) {
    int fb = flags[1];
    int gid = blockIdx.x * 256 + threadIdx.x;
    int row = gid >> 5;  // 32 4-elem chunks per 128-feat row
    float d = dinv[row];
    float vx, vy, vz, vw;
    if (fb) {
        ushort4 v = ((const ushort4*)x)[gid];
        vx = b2f(v.x); vy = b2f(v.y); vz = b2f(v.z); vw = b2f(v.w);
    } else {
        float4 v = ((const float4*)x)[gid];
        vx = v.x; vy = v.y; vz = v.z; vw = v.w;
    }
    ((unsigned*)xs8)[gid] = pk4_fp8(vx * d, vy * d, vz * d, vw * d);
}

// ---- layer-1 GEMM only: H1s8 = fp8(relu((aggX@W1)*dinv + b1) * dinv) ----
// W2 is COMMUTED past aggregation+pooling (both row-linear):
// pool(agg(relu(H1)@W2)) = pool(agg(relu(H1)))@W2 — the 50000-row layer-2 GEMM
// is deleted; a [256x256] GEMV in k_poolfinal replaces it. The trailing *dinv
// is layer-2's source-side prescale (was carried by XW2s8). One fewer rounding
// than r13 (no bf16 H1 intermediate). LDS drops 51.2 -> 17.4 KB.
__global__ __launch_bounds__(256) void k_gcn1(const unsigned short* __restrict__ A,
                                              const unsigned short* __restrict__ B1t,
                                              unsigned char* __restrict__ C8, int M,
                                              const float* __restrict__ dinv,
                                              const void* __restrict__ bias1,
                                              const int* __restrict__ flags) {
    __shared__ unsigned short As1[64 * 136];  // 17.4 KB aggX tile; reused as fp8 C-stage
    int t = threadIdx.x;
    int lane = t & 63;
    int w = t >> 6;               // wave -> 64-col slice
    int bm = blockIdx.x * 64;
    int l15 = lane & 15, quad = lane >> 4;
    int fb = flags[1];

    // ---- stage aggX tile (rows >= M read adjacent workspace; discarded later)
    {
        const uint4* src = (const uint4*)&A[(size_t)bm * 128];
#pragma unroll
        for (int j = 0; j < 4; ++j) {
            int f = t + j * 256;           // uint4 index 0..1023 (16 per row)
            int row = f >> 4, cu = f & 15;
            *(uint4*)&As1[row * 136 + cu * 8] = src[(size_t)row * 16 + cu];
        }
    }
    __syncthreads();

    f32x4 acc[4][4];
#pragma unroll
    for (int ar = 0; ar < 4; ++ar)
#pragma unroll
        for (int tt = 0; tt < 4; ++tt) acc[ar][tt] = (f32x4){0.f, 0.f, 0.f, 0.f};

    // ---- K=128 (A from LDS, B1 from L2)
#pragma unroll
    for (int ks = 0; ks < 4; ++ks) {
        short8 a[4], b[4];
#pragma unroll
        for (int ar = 0; ar < 4; ++ar)
            a[ar] = *(const short8*)&As1[(ar * 16 + l15) * 136 + ks * 32 + quad * 8];
#pragma unroll
        for (int tt = 0; tt < 4; ++tt)
            b[tt] = *(const short8*)&B1t[(size_t)(w * 64 + tt * 16 + l15) * 128 + ks * 32 + quad * 8];
#pragma unroll
        for (int tt = 0; tt < 4; ++tt)
#pragma unroll
            for (int ar = 0; ar < 4; ++ar)
                acc[ar][tt] = __builtin_amdgcn_mfma_f32_16x16x32_bf16(b[tt], a[ar], acc[ar][tt], 0, 0, 0);
    }

    float drow[4];
#pragma unroll
    for (int ar = 0; ar < 4; ++ar) {
        int row = bm + ar * 16 + l15;
        drow[ar] = (row < M) ? dinv[row] : 1.f;
    }
    // epilogue: fp8(relu(acc*dinv + b1) * dinv) via LDS-transpose C-stage
    __syncthreads();                 // all LDS reads of As1 done before overwrite
    unsigned* Cs = (unsigned*)As1;   // row stride 68 dwords (272 B, 16B-aligned)
#pragma unroll
    for (int tt = 0; tt < 4; ++tt) {
        int colb = w * 64 + tt * 16 + quad * 4;
        float bc[4];
#pragma unroll
        for (int rr = 0; rr < 4; ++rr) bc[rr] = LF(bias1, colb + rr, fb);
#pragma unroll
        for (int ar = 0; ar < 4; ++ar) {
            float v0 = fmaxf(fmaf(acc[ar][tt][0], drow[ar], bc[0]), 0.f) * drow[ar];
            float v1 = fmaxf(fmaf(acc[ar][tt][1], drow[ar], bc[1]), 0.f) * drow[ar];
            float v2 = fmaxf(fmaf(acc[ar][tt][2], drow[ar], bc[2]), 0.f) * drow[ar];
            float v3 = fmaxf(fmaf(acc[ar][tt][3], drow[ar], bc[3]), 0.f) * drow[ar];
            Cs[(ar * 16 + l15) * 68 + w * 16 + tt * 4 + quad] = pk4_fp8(v0, v1, v2, v3);
        }
    }
    __syncthreads();
    int r = t >> 2, h = t & 3;       // 64 rows x 4 chunks of 64 B
    if (bm + r < M) {
        const unsigned* src = Cs + r * 68 + h * 16;
        uint4* dst = (uint4*)&C8[(size_t)(bm + r) * 256 + h * 64];
#pragma unroll
        for (int j = 0; j < 4; ++j) dst[j] = *(const uint4*)(src + j * 4);
    }
}

// ---- agg over 128-feat fp8 rows, XCD-aligned block map (64-row groups) ----
__global__ __launch_bounds__(256) void k_agg2(const unsigned char* __restrict__ XS,
                                              const int* __restrict__ rowptr, const int* __restrict__ col,
                                              unsigned short* __restrict__ Hout, int N) {
    int jb = blockIdx.x;
    int x8 = jb & 7, k = jb >> 3;
    int gIdx = k >> 4, win = k & 15;
    int node0 = (gIdx * 8 + x8) * 64 + win * 4;
    int lane = threadIdx.x & 63;
    int i = node0 + (threadIdx.x >> 6);
    if (i >= N) return;
    int fo = lane * 2;
    unsigned sv = *(const unsigned short*)&XS[(size_t)i * 128 + fo];
    f32x2 a = cvt2lo(sv);
    int s = rowptr[i], e = rowptr[i + 1];
    int j = s;
    while (j + 16 <= e) {
        unsigned v[16];
#pragma unroll
        for (int q = 0; q < 16; ++q)
            v[q] = *(const unsigned short*)&XS[(size_t)col[j + q] * 128 + fo];
#pragma unroll
        for (int q = 0; q < 16; ++q) a += cvt2lo(v[q]);
        j += 16;
    }
    if (j + 8 <= e) {
        unsigned v[8];
#pragma unroll
        for (int q = 0; q < 8; ++q)
            v[q] = *(const unsigned short*)&XS[(size_t)col[j + q] * 128 + fo];
#pragma unroll
        for (int q = 0; q < 8; ++q) a += cvt2lo(v[q]);
        j += 8;
    }
    if (j + 4 <= e) {
        unsigned v[4];
#pragma unroll
        for (int q = 0; q < 4; ++q)
            v[q] = *(const unsigned short*)&XS[(size_t)col[j + q] * 128 + fo];
#pragma unroll
        for (int q = 0; q < 4; ++q) a += cvt2lo(v[q]);
        j += 4;
    }
    for (; j < e; ++j)
        a += cvt2lo(*(const unsigned short*)&XS[(size_t)col[j] * 128 + fo]);
    ushort2 o;
    o.x = f2b(a[0]); o.y = f2b(a[1]);
    *(ushort2*)&Hout[(size_t)i * 128 + fo] = o;
}

// ---- agg over 256-feat fp8 H1s8 rows -> per-block f32 POOL PARTIALS ----
// (r13-validated structure; input is now H1s8 = prescaled relu(H1)*dinv.)
__global__ __launch_bounds__(256) void k_agg4p(const unsigned char* __restrict__ XW,
                                               const int* __restrict__ rowptr, const int* __restrict__ col,
                                               const float* __restrict__ dinv,
                                               const int* __restrict__ batch,
                                               const int* __restrict__ flags,
                                               float* __restrict__ partial,
                                               float* __restrict__ pooledX, int N) {
    __shared__ float red[4][256];
    __shared__ int gs[4];
    int t = threadIdx.x;
    int lane = t & 63, sub = t >> 6;
    int i = blockIdx.x * 4 + sub;
    int fo = lane * 4;
    float v[4] = {0.f, 0.f, 0.f, 0.f};
    int g = -1;
    if (i < N) {
        g = IG(batch, i, flags[0]);
        unsigned sv = *(const unsigned*)&XW[(size_t)i * 256 + fo];
        f32x2 a01 = cvt2lo(sv), a23 = cvt2hi(sv);
        int s = rowptr[i], e = rowptr[i + 1];
        int j = s;
        while (j + 16 <= e) {
            unsigned vv[16];
#pragma unroll
            for (int q = 0; q < 16; ++q)
                vv[q] = *(const unsigned*)&XW[(size_t)col[j + q] * 256 + fo];
#pragma unroll
            for (int q = 0; q < 16; ++q) { a01 += cvt2lo(vv[q]); a23 += cvt2hi(vv[q]); }
            j += 16;
        }
        if (j + 8 <= e) {
            unsigned vv[8];
#pragma unroll
            for (int q = 0; q < 8; ++q)
                vv[q] = *(const unsigned*)&XW[(size_t)col[j + q] * 256 + fo];
#pragma unroll
            for (int q = 0; q < 8; ++q) { a01 += cvt2lo(vv[q]); a23 += cvt2hi(vv[q]); }
            j += 8;
        }
        if (j + 4 <= e) {
            unsigned vv[4];
#pragma unroll
            for (int q = 0; q < 4; ++q)
                vv[q] = *(const unsigned*)&XW[(size_t)col[j + q] * 256 + fo];
#pragma unroll
            for (int q = 0; q < 4; ++q) { a01 += cvt2lo(vv[q]); a23 += cvt2hi(vv[q]); }
            j += 4;
        }
        for (; j < e; ++j) {
            unsigned vv = *(const unsigned*)&XW[(size_t)col[j] * 256 + fo];
            a01 += cvt2lo(vv); a23 += cvt2hi(vv);
        }
        float di = dinv[i];
        v[0] = a01[0] * di; v[1] = a01[1] * di;
        v[2] = a23[0] * di; v[3] = a23[1] * di;
    }
    if (lane == 0) gs[sub] = g;
#pragma unroll
    for (int k2 = 0; k2 < 4; ++k2) red[sub][fo + k2] = v[k2];
    __syncthreads();
    bool uni = (gs[0] >= 0) && gs[0] == gs[1] && gs[1] == gs[2] && gs[2] == gs[3];
    if (uni) {
        float s4 = red[0][t] + red[1][t] + red[2][t] + red[3][t];
        partial[(size_t)blockIdx.x * 256 + t] = s4;
    } else if (g >= 0) {
#pragma unroll
        for (int k2 = 0; k2 < 4; ++k2)
            atomicAdd(&pooledX[g * 256 + fo + k2], v[k2]);
    }
}

// ---- classifier: mean-pool partials, then @W2 + b2 (commuted layer-2 GEMV),
// then @Wlin + blin. One 512-thread block per graph. ----
__global__ __launch_bounds__(512) void k_poolfinal(const float* __restrict__ partial,
                                                   const float* __restrict__ pooledX,
                                                   const int* __restrict__ gstart,
                                                   const unsigned short* __restrict__ w2t,
                                                   const void* __restrict__ b2,
                                                   const void* __restrict__ Wlin,
                                                   const void* __restrict__ blin,
                                                   const int* __restrict__ flags,
                                                   void* __restrict__ outv) {
    __shared__ float red[8][256];
    __shared__ float p[256];
    __shared__ float q[256];
    int g = blockIdx.x, t = threadIdx.x;
    int sub = t >> 6, lane = t & 63;
    int s = gstart[g], e = gstart[g + 1];
    int cnt = e - s;
    int b0 = (s + 3) >> 2, b1 = e >> 2;   // fully-inside partial blocks [b0, b1)
    int fo = lane * 4;
    float a0 = 0.f, a1 = 0.f, a2 = 0.f, a3 = 0.f;
    for (int b = b0 + sub; b < b1; b += 8) {
        float4 v = *(const float4*)&partial[(size_t)b * 256 + fo];
        a0 += v.x; a1 += v.y; a2 += v.z; a3 += v.w;
    }
    red[sub][fo + 0] = a0;
    red[sub][fo + 1] = a1;
    red[sub][fo + 2] = a2;
    red[sub][fo + 3] = a3;
    __syncthreads();
    int fb = flags[1];
    if (t < 256) {
        float sum8 = pooledX[g * 256 + t];
#pragma unroll
        for (int qq = 0; qq < 8; ++qq) sum8 += red[qq][t];
        float inv = 1.f / fmaxf((float)cnt, 1.f);
        p[t] = sum8 * inv;                  // mean of agg(relu(H1)*dinv)*dinv
    }
    __syncthreads();
    if (t < 256) {
        // q[t] = p @ W2[:,t] + b2[t]  (w2t row t = W2 column t, bf16)
        float acc2 = (cnt > 0) ? LF(b2, t, fb) : 0.f;
        const unsigned short* wr = &w2t[(size_t)t * 256];
        for (int k = 0; k < 256; k += 8) {
            short8 v8 = *(const short8*)&wr[k];
#pragma unroll
            for (int j = 0; j < 8; ++j)
                acc2 = fmaf(p[k + j], b2f((unsigned short)v8[j]), acc2);
        }
        q[t] = acc2;
    }
    __syncthreads();
    if (t < N_CLS) {
        float sum = LF(blin, t, fb);
        for (int f = 0; f < HID; ++f) sum = fmaf(q[f], LF(Wlin, f * N_CLS + t, fb), sum);
        if (fb) ((bf16*)outv)[g * N_CLS + t] = __float2bfloat16(sum);
        else    ((float*)outv)[g * N_CLS + t] = sum;
    }
}

extern "C" void kernel_launch(void* const* d_in, const int* in_sizes, int n_in,
                              void* d_out, int out_size, void* d_ws, size_t ws_size,
                              hipStream_t stream) {
    (void)n_in; (void)ws_size; (void)in_sizes; (void)out_size;
    const void* x     = d_in[0];
    const int*  ei    = (const int*)d_in[1];
    const int*  batch = (const int*)d_in[2];
    const void* W1    = d_in[3];
    const void* b1    = d_in[4];
    const void* W2    = d_in[5];
    const void* b2    = d_in[6];
    const void* Wl    = d_in[7];
    const void* bl    = d_in[8];

    const int N = N_NODES, E = N_EDGES, F = IN_F, H = HID, G = N_GRAPH;

    char* ws = (char*)d_ws;
    size_t off = 0;
    auto alloc = [&](size_t bytes) -> void* {
        void* p = ws + off;
        off += (bytes + 511) & ~(size_t)511;
        return p;
    };
    unsigned char*  xs8  = (unsigned char*)alloc((size_t)N * F);       // fp8 prescaled x (6.4 MB)
    unsigned short* aggX = (unsigned short*)alloc((size_t)N * F * 2);  // bf16 A-partial @ x (12.8 MB)
    unsigned char*  H1s8 = (unsigned char*)alloc((size_t)N * H);       // fp8 relu(H1)*dinv (12.8 MB) — must NOT alias aggX (k_gcn1 reads aggX while writing this)
    float*          partial = (float*)alloc((size_t)(N / 4) * H * 4);  // f32 pool partials (12.8 MB)
    float*          pooledX = (float*)alloc((size_t)G * H * 4);        // boundary atomics (256 KB, zeroed)
    unsigned short* w1t  = (unsigned short*)alloc((size_t)H * F * 2);
    unsigned short* w2t  = (unsigned short*)alloc((size_t)H * H * 2);
    int*   bucketCnt = (int*)alloc((size_t)NB * 16 * 4);   // zero region (padded: 1 line/bucket)
    int*   bucketBase = (int*)alloc((size_t)(NB + 1) * 4);
    int*   blockBase = (int*)alloc((size_t)PBLOCKS * NB * 4);
    unsigned* part  = (unsigned*)alloc((size_t)E * 4);     // packed (d&511)<<16 | s
    int*   gstart  = (int*)alloc((size_t)(G + 1) * 4);
    float* dinv    = (float*)alloc((size_t)N * 4);
    int*   rowptr  = (int*)alloc((size_t)(N + 1) * 4);
    int*   flags   = (int*)alloc(512);
    int*   col     = (int*)alloc((size_t)E * 4);
    size_t zero_bytes = (size_t)NB * 16 * 4;

    hipMemsetAsync(bucketCnt, 0, zero_bytes, stream);
    hipMemsetAsync(pooledX, 0, (size_t)G * H * 4, stream);

    // A1 (edge histogram with local detect) + flags writer (block 256)
    k_partA1<<<PBLOCKS + 1, 256, 0, stream>>>(ei, bucketCnt, blockBase,
                                              (const unsigned short*)x, flags, E, N);
    k_bscan<<<1, 128, 0, stream>>>(bucketCnt, bucketBase);
    k_partA2<<<PBLOCKS, 256, 0, stream>>>(ei, bucketBase, blockBase, part, flags, E, N);
    // partB buckets + merged weight transposes + gstart
    k_partB<<<PB_TOT, 256, 0, stream>>>(part, bucketBase, rowptr, dinv, col,
                                        W1, w1t, W2, w2t, batch, gstart, flags, N);
    // xs8 = fp8(x * dinv)
    k_cvt<<<CVTX_BLOCKS, 256, 0, stream>>>(x, dinv, xs8, flags);

    int g64 = (N + 63) >> 6;                   // 782 64-row blocks
    int aggBlocks = ((g64 + 7) >> 3) * 8 * 16; // 12544: XCD-aligned agg2 map
    int nbAgg = (N + 3) / 4;                   // 12500 (N divisible by 4)

    // layer-1 aggregate, layer-1 GEMM (W2 commuted out), layer-2 aggregate -> pool partials
    k_agg2<<<aggBlocks, 256, 0, stream>>>(xs8, rowptr, col, aggX, N);
    k_gcn1<<<g64, 256, 0, stream>>>(aggX, w1t, H1s8, N, dinv, b1, flags);
    k_agg4p<<<nbAgg, 256, 0, stream>>>(H1s8, rowptr, col, dinv, batch, flags, partial, pooledX, N);
    // classifier: mean-pool, @W2+b2 (commuted GEMV), @Wlin+blin
    k_poolfinal<<<G, 512, 0, stream>>>(partial, pooledX, gstart, w2t, b2, Wl, bl, flags, d_out);
}

// Round 15
// 236.662 us; speedup vs baseline: 1.2588x; 1.0249x over previous
//
#include <hip/hip_runtime.h>
#include <hip/hip_bf16.h>

typedef __hip_bfloat16 bf16;
typedef __attribute__((ext_vector_type(8))) short short8;
typedef __attribute__((ext_vector_type(4))) float f32x4;
typedef __attribute__((ext_vector_type(2))) float f32x2;

// ---- problem constants (fixed by reference file) ----
#define N_NODES 50000
#define N_EDGES 800000
#define IN_F    128
#define HID     256
#define N_CLS   10
#define N_GRAPH 256

// radix-partition CSR build
#define NB 98          // buckets = ceil(N / 512), bucket = d >> 9
#define PBLOCKS 256    // edge blocks in k_part1
#define CAP 16384      // padded per-bucket capacity (avg 8163, max ~8600 for uniform E)

// flags[0] = ints are int64 (read low words), flags[1] = floats are bf16
__device__ __forceinline__ int IG(const int* __restrict__ p, int i, int w) {
    return w ? p[2 * i] : p[i];
}
__device__ __forceinline__ float LF(const void* __restrict__ p, int i, int isbf) {
    return isbf ? __bfloat162float(((const bf16*)p)[i]) : ((const float*)p)[i];
}
__device__ __forceinline__ float b2f(unsigned short h) {
    union { unsigned u; float f; } c; c.u = ((unsigned)h) << 16; return c.f;
}
__device__ __forceinline__ unsigned short f2b(float x) {
    bf16 h = __float2bfloat16(x);
    union { bf16 b; unsigned short u; } c; c.b = h; return c.u;
}
// fp8 e4m3 byte -> float scaled by 2^-120 (fallback decode path)
__device__ __forceinline__ float f8s(unsigned b) {
    union { unsigned u; float f; } c;
    c.u = ((b & 0x80u) << 24) | ((b & 0x7Fu) << 20);
    return c.f;
}
#define F8SCALE 0x1p120f
// float -> OCP fp8 e4m3 (RTNE via bf16 intermediate; FTZ below subnormal range)
__device__ __forceinline__ unsigned f2fp8(float x) {
    unsigned short h = f2b(x * 0x1p-120f);
    unsigned s = ((unsigned)h >> 8) & 0x80u;
    unsigned mag = (unsigned)h & 0x7FFFu;
    unsigned r = (mag + 7u + ((mag >> 4) & 1u)) >> 4;
    if (r > 0x7Eu) r = 0x7Eu;
    return s | r;
}

#if defined(__has_builtin)
#if __has_builtin(__builtin_amdgcn_cvt_pk_f32_fp8)
#define HW_FP8 1
#endif
#if __has_builtin(__builtin_amdgcn_cvt_pk_fp8_f32)
#define HW_FP8E 1
#endif
#endif

// decode 2 fp8 bytes (low or high half of a dword) -> float2, true magnitudes
__device__ __forceinline__ f32x2 cvt2lo(unsigned v) {
#ifdef HW_FP8
    return __builtin_amdgcn_cvt_pk_f32_fp8((int)v, false);
#else
    f32x2 r; r[0] = f8s(v & 0xFF) * F8SCALE; r[1] = f8s((v >> 8) & 0xFF) * F8SCALE; return r;
#endif
}
__device__ __forceinline__ f32x2 cvt2hi(unsigned v) {
#ifdef HW_FP8
    return __builtin_amdgcn_cvt_pk_f32_fp8((int)v, true);
#else
    f32x2 r; r[0] = f8s((v >> 16) & 0xFF) * F8SCALE; r[1] = f8s(v >> 24) * F8SCALE; return r;
#endif
}
// pack 4 floats -> 4 fp8 bytes (HW packed cvt when available)
__device__ __forceinline__ unsigned pk4_fp8(float v0, float v1, float v2, float v3) {
#ifdef HW_FP8E
    int o = __builtin_amdgcn_cvt_pk_fp8_f32(v0, v1, 0, false);
    o = __builtin_amdgcn_cvt_pk_fp8_f32(v2, v3, o, true);
    return (unsigned)o;
#else
    return f2fp8(v0) | (f2fp8(v1) << 8) | (f2fp8(v2) << 16) | (f2fp8(v3) << 24);
#endif
}

// ---- SINGLE-PASS edge partition + flags writer ----
// Each thread holds its <=13 packed edges in REGISTERS between the histogram
// and scatter phases: count -> global per-bucket reservation -> scatter into
// bucket-PADDED part array (bucket b occupies [b*CAP, b*CAP+cnt_b)). Deletes
// the old partA2 launch, its 12.8MB edge re-read, its duplicate histogram,
// and the fragile A1/A2 identical-iteration contract. block PBLOCKS: flags.
__global__ __launch_bounds__(256) void k_part1(const int* __restrict__ ei, int* __restrict__ bucketCnt,
                                               unsigned* __restrict__ part,
                                               const unsigned short* __restrict__ x,
                                               int* __restrict__ flags, int E, int N) {
    int t = threadIdx.x;
    if (blockIdx.x == PBLOCKS) {
        __shared__ int nz, cnt;
        if (t == 0) { nz = 0; cnt = 0; }
        __syncthreads();
        int found = 0, c = 0;
        for (int s = 0; s < 4; ++s) {
            int idx = 2 * (t * 4 + s) + 1;
            if (ei[idx] != 0) found = 1;
        }
        for (int s = 0; s < 8; ++s) {
            unsigned short h = x[t * 8 + s];
            int e = (h >> 7) & 0xFF;
            if (e >= 110 && e <= 135) c++;
        }
        if (found) atomicAdd(&nz, 1);
        atomicAdd(&cnt, c);
        __syncthreads();
        if (t == 0) {
            flags[0] = (nz == 0) ? 1 : 0;
            flags[1] = (cnt > 1536) ? 1 : 0;
        }
        return;
    }
    __shared__ int h[NB];
    __shared__ int wsh;
    if (t == 0) wsh = 0;
    if (t < NB) h[t] = 0;
    __syncthreads();
    int found = 0;
    for (int s = 0; s < 4; ++s) {
        int idx = 2 * (t * 4 + s) + 1;
        if (ei[idx] != 0) found = 1;
    }
    if (found) atomicAdd(&wsh, 1);
    __syncthreads();
    int w = (wsh == 0) ? 1 : 0;
    // pass 1: read edges once into registers, LDS histogram
    unsigned ed[13];
#pragma unroll
    for (int k = 0; k < 13; ++k) {
        int e = blockIdx.x * 256 + t + k * (PBLOCKS * 256);
        unsigned val = 0xFFFFFFFFu;   // unreachable for valid edges (bucket<=97, s<50000)
        if (e < E) {
            int d = IG(ei, E + e, w);
            int s = IG(ei, e, w);
            if ((unsigned)d < (unsigned)N && (unsigned)s < (unsigned)N) {
                val = ((unsigned)(d >> 9) << 25) | ((unsigned)(d & 511) << 16) | (unsigned)s;
                atomicAdd(&h[d >> 9], 1);
            }
        }
        ed[k] = val;
    }
    __syncthreads();
    // reserve global per-bucket ranges; h becomes this block's cursor base
    if (t < NB) h[t] = atomicAdd(&bucketCnt[t * 16], h[t]);
    __syncthreads();
    // pass 2: scatter from registers into padded part
#pragma unroll
    for (int k = 0; k < 13; ++k) {
        unsigned val = ed[k];
        if (val != 0xFFFFFFFFu) {
            int bkt = (int)(val >> 25);
            int slot = atomicAdd(&h[bkt], 1);
            part[(size_t)bkt * CAP + slot] = val & 0x01FFFFFFu;
        }
    }
}

// ---- 1-block exclusive scan of bucket counts -> compact bases ----
__global__ __launch_bounds__(128) void k_bscan(const int* __restrict__ bucketCnt,
                                               int* __restrict__ bucketBase) {
    __shared__ int s[128];
    int t = threadIdx.x;
    int v = (t < NB) ? bucketCnt[t * 16] : 0;
    s[t] = v;
    __syncthreads();
    for (int off = 1; off < 128; off <<= 1) {
        int add = (t >= off) ? s[t - off] : 0;
        __syncthreads();
        s[t] += add;
        __syncthreads();
    }
    if (t <= NB) bucketBase[t] = (t < NB) ? (s[t] - v) : s[NB - 1] + 0;
    if (t == NB - 1) bucketBase[NB] = s[t];  // total kept edges
}

// ---- partition pass B (+ merged weight transposes + gstart) ----
// blocks 0..97: per-bucket rowptr/dinv/col — reads bucket b's entries from the
// PADDED part at [b*CAP, b*CAP+cnt) and writes COMPACT col at bucketBase[b].
// 98..225: w1t. 226..481: w2t. 482..677: graph-start bounds.
#define PB_W1 98
#define PB_W2 226
#define PB_GB 482
#define PB_TOT 678
__global__ __launch_bounds__(256) void k_partB(const unsigned* __restrict__ part,
                                               const int* __restrict__ bucketCnt,
                                               const int* __restrict__ bucketBase,
                                               int* __restrict__ rowptr, float* __restrict__ dinv,
                                               int* __restrict__ col,
                                               const void* __restrict__ W1, unsigned short* __restrict__ w1t,
                                               const void* __restrict__ W2, unsigned short* __restrict__ w2t,
                                               const int* __restrict__ batch, int* __restrict__ gstart,
                                               const int* __restrict__ flags, int N) {
    int b = blockIdx.x, t = threadIdx.x;
    if (b >= NB) {
        int fb = flags[1];
        if (b < PB_W2) {
            int i = (b - PB_W1) * 256 + t;
            int n = i >> 7, k = i & 127;
            w1t[i] = f2b(LF(W1, k * 256 + n, fb));
        } else if (b < PB_GB) {
            int i = (b - PB_W2) * 256 + t;
            int n = i >> 8, k = i & 255;
            w2t[i] = f2b(LF(W2, k * 256 + n, fb));
        } else {
            int i = (b - PB_GB) * 256 + t;
            if (i <= N_NODES) {
                int w = flags[0];
                int prev = (i == 0) ? -1 : IG(batch, i - 1, w);
                int cur  = (i == N_NODES) ? N_GRAPH : IG(batch, i, w);
                if (prev < -1) prev = -1;
                if (cur > N_GRAPH) cur = N_GRAPH;
                for (int g = prev + 1; g <= cur; ++g)
                    if (g >= 0 && g <= N_GRAPH) gstart[g] = i;
            }
        }
        return;
    }
    __shared__ int hist[512];
    __shared__ int scn[512];
    __shared__ int pair[256];
    size_t s0p = (size_t)b * CAP;            // padded source base
    int cnt = bucketCnt[b * 16];
    int s0c = bucketBase[b];                 // compact destination base
    hist[t] = 0; hist[t + 256] = 0;
    __syncthreads();
    for (int j = t; j < cnt; j += 256)
        atomicAdd(&hist[part[s0p + j] >> 16], 1);
    __syncthreads();
    // exclusive scan over 512 via pair-sums
    int a0 = hist[2 * t], a1 = hist[2 * t + 1];
    int pv = a0 + a1;
    pair[t] = pv;
    __syncthreads();
    for (int off = 1; off < 256; off <<= 1) {
        int add = (t >= off) ? pair[t - off] : 0;
        __syncthreads();
        pair[t] += add;
        __syncthreads();
    }
    int pbase = pair[t] - pv;  // exclusive pair base
    scn[2 * t] = pbase;
    scn[2 * t + 1] = pbase + a0;
    __syncthreads();
#pragma unroll
    for (int hh = 0; hh < 2; ++hh) {
        int l = t + hh * 256;
        int node = b * 512 + l;
        if (node < N) {
            rowptr[node] = s0c + scn[l];
            dinv[node] = rsqrtf((float)(hist[l] + 1));  // +1 self loop
        }
    }
    if (b == 0 && t == 0) rowptr[N] = bucketBase[NB];
    // reuse scn as cursors (already = local base)
    __syncthreads();
    for (int j = t; j < cnt; j += 256) {
        unsigned p = part[s0p + j];
        int pos = s0c + atomicAdd(&scn[p >> 16], 1);
        col[pos] = (int)(p & 0xFFFFu);
    }
}

// ---- xs8 = fp8(x*dinv) ----
#define CVTX_BLOCKS 6250   // N*IN_F/4 / 256
__global__ __launch_bounds__(256) void k_cvt(const void* __restrict__ x, const float* __restrict__ dinv,
                                             unsigned char* __restrict__ xs8,
                                             const int* __restrict__ flags) {
    int fb = flags[1];
    int gid = blockIdx.x * 256 + threadIdx.x;
    int row = gid >> 5;  // 32 4-elem chunks per 128-feat row
    float d = dinv[row];
    float vx, vy, vz, vw;
    if (fb) {
        ushort4 v = ((const ushort4*)x)[gid];
        vx = b2f(v.x); vy = b2f(v.y); vz = b2f(v.z); vw = b2f(v.w);
    } else {
        float4 v = ((const float4*)x)[gid];
        vx = v.x; vy = v.y; vz = v.z; vw = v.w;
    }
    ((unsigned*)xs8)[gid] = pk4_fp8(vx * d, vy * d, vz * d, vw * d);
}

// ---- layer-1 GEMM only: H1s8 = fp8(relu((aggX@W1)*dinv + b1) * dinv) ----
// (r14-validated: W2 commuted past aggregation+pooling; layer-2 GEMM replaced
// by a [256x256] GEMV in k_poolfinal.)
__global__ __launch_bounds__(256) void k_gcn1(const unsigned short* __restrict__ A,
                                              const unsigned short* __restrict__ B1t,
                                              unsigned char* __restrict__ C8, int M,
                                              const float* __restrict__ dinv,
                                              const void* __restrict__ bias1,
                                              const int* __restrict__ flags) {
    __shared__ unsigned short As1[64 * 136];  // 17.4 KB aggX tile; reused as fp8 C-stage
    int t = threadIdx.x;
    int lane = t & 63;
    int w = t >> 6;               // wave -> 64-col slice
    int bm = blockIdx.x * 64;
    int l15 = lane & 15, quad = lane >> 4;
    int fb = flags[1];

    // ---- stage aggX tile (rows >= M read adjacent workspace; discarded later)
    {
        const uint4* src = (const uint4*)&A[(size_t)bm * 128];
#pragma unroll
        for (int j = 0; j < 4; ++j) {
            int f = t + j * 256;           // uint4 index 0..1023 (16 per row)
            int row = f >> 4, cu = f & 15;
            *(uint4*)&As1[row * 136 + cu * 8] = src[(size_t)row * 16 + cu];
        }
    }
    __syncthreads();

    f32x4 acc[4][4];
#pragma unroll
    for (int ar = 0; ar < 4; ++ar)
#pragma unroll
        for (int tt = 0; tt < 4; ++tt) acc[ar][tt] = (f32x4){0.f, 0.f, 0.f, 0.f};

    // ---- K=128 (A from LDS, B1 from L2)
#pragma unroll
    for (int ks = 0; ks < 4; ++ks) {
        short8 a[4], b[4];
#pragma unroll
        for (int ar = 0; ar < 4; ++ar)
            a[ar] = *(const short8*)&As1[(ar * 16 + l15) * 136 + ks * 32 + quad * 8];
#pragma unroll
        for (int tt = 0; tt < 4; ++tt)
            b[tt] = *(const short8*)&B1t[(size_t)(w * 64 + tt * 16 + l15) * 128 + ks * 32 + quad * 8];
#pragma unroll
        for (int tt = 0; tt < 4; ++tt)
#pragma unroll
            for (int ar = 0; ar < 4; ++ar)
                acc[ar][tt] = __builtin_amdgcn_mfma_f32_16x16x32_bf16(b[tt], a[ar], acc[ar][tt], 0, 0, 0);
    }

    float drow[4];
#pragma unroll
    for (int ar = 0; ar < 4; ++ar) {
        int row = bm + ar * 16 + l15;
        drow[ar] = (row < M) ? dinv[row] : 1.f;
    }
    // epilogue: fp8(relu(acc*dinv + b1) * dinv) via LDS-transpose C-stage
    __syncthreads();                 // all LDS reads of As1 done before overwrite
    unsigned* Cs = (unsigned*)As1;   // row stride 68 dwords (272 B, 16B-aligned)
#pragma unroll
    for (int tt = 0; tt < 4; ++tt) {
        int colb = w * 64 + tt * 16 + quad * 4;
        float bc[4];
#pragma unroll
        for (int rr = 0; rr < 4; ++rr) bc[rr] = LF(bias1, colb + rr, fb);
#pragma unroll
        for (int ar = 0; ar < 4; ++ar) {
            float v0 = fmaxf(fmaf(acc[ar][tt][0], drow[ar], bc[0]), 0.f) * drow[ar];
            float v1 = fmaxf(fmaf(acc[ar][tt][1], drow[ar], bc[1]), 0.f) * drow[ar];
            float v2 = fmaxf(fmaf(acc[ar][tt][2], drow[ar], bc[2]), 0.f) * drow[ar];
            float v3 = fmaxf(fmaf(acc[ar][tt][3], drow[ar], bc[3]), 0.f) * drow[ar];
            Cs[(ar * 16 + l15) * 68 + w * 16 + tt * 4 + quad] = pk4_fp8(v0, v1, v2, v3);
        }
    }
    __syncthreads();
    int r = t >> 2, h = t & 3;       // 64 rows x 4 chunks of 64 B
    if (bm + r < M) {
        const unsigned* src = Cs + r * 68 + h * 16;
        uint4* dst = (uint4*)&C8[(size_t)(bm + r) * 256 + h * 64];
#pragma unroll
        for (int j = 0; j < 4; ++j) dst[j] = *(const uint4*)(src + j * 4);
    }
}

// ---- agg over 128-feat fp8 rows, XCD-aligned block map (64-row groups) ----
__global__ __launch_bounds__(256) void k_agg2(const unsigned char* __restrict__ XS,
                                              const int* __restrict__ rowptr, const int* __restrict__ col,
                                              unsigned short* __restrict__ Hout, int N) {
    int jb = blockIdx.x;
    int x8 = jb & 7, k = jb >> 3;
    int gIdx = k >> 4, win = k & 15;
    int node0 = (gIdx * 8 + x8) * 64 + win * 4;
    int lane = threadIdx.x & 63;
    int i = node0 + (threadIdx.x >> 6);
    if (i >= N) return;
    int fo = lane * 2;
    unsigned sv = *(const unsigned short*)&XS[(size_t)i * 128 + fo];
    f32x2 a = cvt2lo(sv);
    int s = rowptr[i], e = rowptr[i + 1];
    int j = s;
    while (j + 16 <= e) {
        unsigned v[16];
#pragma unroll
        for (int q = 0; q < 16; ++q)
            v[q] = *(const unsigned short*)&XS[(size_t)col[j + q] * 128 + fo];
#pragma unroll
        for (int q = 0; q < 16; ++q) a += cvt2lo(v[q]);
        j += 16;
    }
    if (j + 8 <= e) {
        unsigned v[8];
#pragma unroll
        for (int q = 0; q < 8; ++q)
            v[q] = *(const unsigned short*)&XS[(size_t)col[j + q] * 128 + fo];
#pragma unroll
        for (int q = 0; q < 8; ++q) a += cvt2lo(v[q]);
        j += 8;
    }
    if (j + 4 <= e) {
        unsigned v[4];
#pragma unroll
        for (int q = 0; q < 4; ++q)
            v[q] = *(const unsigned short*)&XS[(size_t)col[j + q] * 128 + fo];
#pragma unroll
        for (int q = 0; q < 4; ++q) a += cvt2lo(v[q]);
        j += 4;
    }
    for (; j < e; ++j)
        a += cvt2lo(*(const unsigned short*)&XS[(size_t)col[j] * 128 + fo]);
    ushort2 o;
    o.x = f2b(a[0]); o.y = f2b(a[1]);
    *(ushort2*)&Hout[(size_t)i * 128 + fo] = o;
}

// ---- agg over 256-feat fp8 H1s8 rows -> per-block f32 POOL PARTIALS ----
__global__ __launch_bounds__(256) void k_agg4p(const unsigned char* __restrict__ XW,
                                               const int* __restrict__ rowptr, const int* __restrict__ col,
                                               const float* __restrict__ dinv,
                                               const int* __restrict__ batch,
                                               const int* __restrict__ flags,
                                               float* __restrict__ partial,
                                               float* __restrict__ pooledX, int N) {
    __shared__ float red[4][256];
    __shared__ int gs[4];
    int t = threadIdx.x;
    int lane = t & 63, sub = t >> 6;
    int i = blockIdx.x * 4 + sub;
    int fo = lane * 4;
    float v[4] = {0.f, 0.f, 0.f, 0.f};
    int g = -1;
    if (i < N) {
        g = IG(batch, i, flags[0]);
        unsigned sv = *(const unsigned*)&XW[(size_t)i * 256 + fo];
        f32x2 a01 = cvt2lo(sv), a23 = cvt2hi(sv);
        int s = rowptr[i], e = rowptr[i + 1];
        int j = s;
        while (j + 16 <= e) {
            unsigned vv[16];
#pragma unroll
            for (int q = 0; q < 16; ++q)
                vv[q] = *(const unsigned*)&XW[(size_t)col[j + q] * 256 + fo];
#pragma unroll
            for (int q = 0; q < 16; ++q) { a01 += cvt2lo(vv[q]); a23 += cvt2hi(vv[q]); }
            j += 16;
        }
        if (j + 8 <= e) {
            unsigned vv[8];
#pragma unroll
            for (int q = 0; q < 8; ++q)
                vv[q] = *(const unsigned*)&XW[(size_t)col[j + q] * 256 + fo];
#pragma unroll
            for (int q = 0; q < 8; ++q) { a01 += cvt2lo(vv[q]); a23 += cvt2hi(vv[q]); }
            j += 8;
        }
        if (j + 4 <= e) {
            unsigned vv[4];
#pragma unroll
            for (int q = 0; q < 4; ++q)
                vv[q] = *(const unsigned*)&XW[(size_t)col[j + q] * 256 + fo];
#pragma unroll
            for (int q = 0; q < 4; ++q) { a01 += cvt2lo(vv[q]); a23 += cvt2hi(vv[q]); }
            j += 4;
        }
        for (; j < e; ++j) {
            unsigned vv = *(const unsigned*)&XW[(size_t)col[j] * 256 + fo];
            a01 += cvt2lo(vv); a23 += cvt2hi(vv);
        }
        float di = dinv[i];
        v[0] = a01[0] * di; v[1] = a01[1] * di;
        v[2] = a23[0] * di; v[3] = a23[1] * di;
    }
    if (lane == 0) gs[sub] = g;
#pragma unroll
    for (int k2 = 0; k2 < 4; ++k2) red[sub][fo + k2] = v[k2];
    __syncthreads();
    bool uni = (gs[0] >= 0) && gs[0] == gs[1] && gs[1] == gs[2] && gs[2] == gs[3];
    if (uni) {
        float s4 = red[0][t] + red[1][t] + red[2][t] + red[3][t];
        partial[(size_t)blockIdx.x * 256 + t] = s4;
    } else if (g >= 0) {
#pragma unroll
        for (int k2 = 0; k2 < 4; ++k2)
            atomicAdd(&pooledX[g * 256 + fo + k2], v[k2]);
    }
}

// ---- classifier: mean-pool partials, then @W2 + b2 (commuted layer-2 GEMV),
// then @Wlin + blin. One 512-thread block per graph. ----
__global__ __launch_bounds__(512) void k_poolfinal(const float* __restrict__ partial,
                                                   const float* __restrict__ pooledX,
                                                   const int* __restrict__ gstart,
                                                   const unsigned short* __restrict__ w2t,
                                                   const void* __restrict__ b2,
                                                   const void* __restrict__ Wlin,
                                                   const void* __restrict__ blin,
                                                   const int* __restrict__ flags,
                                                   void* __restrict__ outv) {
    __shared__ float red[8][256];
    __shared__ float p[256];
    __shared__ float q[256];
    int g = blockIdx.x, t = threadIdx.x;
    int sub = t >> 6, lane = t & 63;
    int s = gstart[g], e = gstart[g + 1];
    int cnt = e - s;
    int b0 = (s + 3) >> 2, b1 = e >> 2;   // fully-inside partial blocks [b0, b1)
    int fo = lane * 4;
    float a0 = 0.f, a1 = 0.f, a2 = 0.f, a3 = 0.f;
    for (int b = b0 + sub; b < b1; b += 8) {
        float4 v = *(const float4*)&partial[(size_t)b * 256 + fo];
        a0 += v.x; a1 += v.y; a2 += v.z; a3 += v.w;
    }
    red[sub][fo + 0] = a0;
    red[sub][fo + 1] = a1;
    red[sub][fo + 2] = a2;
    red[sub][fo + 3] = a3;
    __syncthreads();
    int fb = flags[1];
    if (t < 256) {
        float sum8 = pooledX[g * 256 + t];
#pragma unroll
        for (int qq = 0; qq < 8; ++qq) sum8 += red[qq][t];
        float inv = 1.f / fmaxf((float)cnt, 1.f);
        p[t] = sum8 * inv;                  // mean of agg(relu(H1)*dinv)*dinv
    }
    __syncthreads();
    if (t < 256) {
        // q[t] = p @ W2[:,t] + b2[t]  (w2t row t = W2 column t, bf16)
        float acc2 = (cnt > 0) ? LF(b2, t, fb) : 0.f;
        const unsigned short* wr = &w2t[(size_t)t * 256];
        for (int k = 0; k < 256; k += 8) {
            short8 v8 = *(const short8*)&wr[k];
#pragma unroll
            for (int j = 0; j < 8; ++j)
                acc2 = fmaf(p[k + j], b2f((unsigned short)v8[j]), acc2);
        }
        q[t] = acc2;
    }
    __syncthreads();
    if (t < N_CLS) {
        float sum = LF(blin, t, fb);
        for (int f = 0; f < HID; ++f) sum = fmaf(q[f], LF(Wlin, f * N_CLS + t, fb), sum);
        if (fb) ((bf16*)outv)[g * N_CLS + t] = __float2bfloat16(sum);
        else    ((float*)outv)[g * N_CLS + t] = sum;
    }
}

extern "C" void kernel_launch(void* const* d_in, const int* in_sizes, int n_in,
                              void* d_out, int out_size, void* d_ws, size_t ws_size,
                              hipStream_t stream) {
    (void)n_in; (void)ws_size; (void)in_sizes; (void)out_size;
    const void* x     = d_in[0];
    const int*  ei    = (const int*)d_in[1];
    const int*  batch = (const int*)d_in[2];
    const void* W1    = d_in[3];
    const void* b1    = d_in[4];
    const void* W2    = d_in[5];
    const void* b2    = d_in[6];
    const void* Wl    = d_in[7];
    const void* bl    = d_in[8];

    const int N = N_NODES, E = N_EDGES, F = IN_F, H = HID, G = N_GRAPH;

    char* ws = (char*)d_ws;
    size_t off = 0;
    auto alloc = [&](size_t bytes) -> void* {
        void* p = ws + off;
        off += (bytes + 511) & ~(size_t)511;
        return p;
    };
    unsigned char*  xs8  = (unsigned char*)alloc((size_t)N * F);       // fp8 prescaled x (6.4 MB)
    unsigned short* aggX = (unsigned short*)alloc((size_t)N * F * 2);  // bf16 A-partial @ x (12.8 MB)
    unsigned char*  H1s8 = (unsigned char*)alloc((size_t)N * H);       // fp8 relu(H1)*dinv (12.8 MB) — must NOT alias aggX (k_gcn1 reads aggX while writing this)
    float*          partial = (float*)alloc((size_t)(N / 4) * H * 4);  // f32 pool partials (12.8 MB)
    float*          pooledX = (float*)alloc((size_t)G * H * 4);        // boundary atomics (256 KB, zeroed)
    unsigned short* w1t  = (unsigned short*)alloc((size_t)H * F * 2);
    unsigned short* w2t  = (unsigned short*)alloc((size_t)H * H * 2);
    int*   bucketCnt = (int*)alloc((size_t)NB * 16 * 4);   // zero region (padded: 1 line/bucket)
    int*   bucketBase = (int*)alloc((size_t)(NB + 1) * 4);
    unsigned* part  = (unsigned*)alloc((size_t)NB * CAP * 4);  // bucket-PADDED packed edges (6.4 MB)
    int*   gstart  = (int*)alloc((size_t)(G + 1) * 4);
    float* dinv    = (float*)alloc((size_t)N * 4);
    int*   rowptr  = (int*)alloc((size_t)(N + 1) * 4);
    int*   flags   = (int*)alloc(512);
    int*   col     = (int*)alloc((size_t)E * 4);
    size_t zero_bytes = (size_t)NB * 16 * 4;

    hipMemsetAsync(bucketCnt, 0, zero_bytes, stream);
    hipMemsetAsync(pooledX, 0, (size_t)G * H * 4, stream);

    // single-pass edge partition (registers between count & scatter) + flags
    k_part1<<<PBLOCKS + 1, 256, 0, stream>>>(ei, bucketCnt, part,
                                             (const unsigned short*)x, flags, E, N);
    k_bscan<<<1, 128, 0, stream>>>(bucketCnt, bucketBase);
    // partB buckets (padded->compact) + merged weight transposes + gstart
    k_partB<<<PB_TOT, 256, 0, stream>>>(part, bucketCnt, bucketBase, rowptr, dinv, col,
                                        W1, w1t, W2, w2t, batch, gstart, flags, N);
    // xs8 = fp8(x * dinv)
    k_cvt<<<CVTX_BLOCKS, 256, 0, stream>>>(x, dinv, xs8, flags);

    int g64 = (N + 63) >> 6;                   // 782 64-row blocks
    int aggBlocks = ((g64 + 7) >> 3) * 8 * 16; // 12544: XCD-aligned agg2 map
    int nbAgg = (N + 3) / 4;                   // 12500 (N divisible by 4)

    // layer-1 aggregate, layer-1 GEMM (W2 commuted out), layer-2 aggregate -> pool partials
    k_agg2<<<aggBlocks, 256, 0, stream>>>(xs8, rowptr, col, aggX, N);
    k_gcn1<<<g64, 256, 0, stream>>>(aggX, w1t, H1s8, N, dinv, b1, flags);
    k_agg4p<<<nbAgg, 256, 0, stream>>>(H1s8, rowptr, col, dinv, batch, flags, partial, pooledX, N);
    // classifier: mean-pool, @W2+b2 (commuted GEMV), @Wlin+blin
    k_poolfinal<<<G, 512, 0, stream>>>(partial, pooledX, gstart, w2t, b2, Wl, bl, flags, d_out);
}